// Round 1
// baseline (363.069 us; speedup 1.0000x reference)
//
#include <hip/hip_runtime.h>
#include <stdint.h>

typedef unsigned short u16;
typedef unsigned int   u32;
typedef __bf16  bf16x8 __attribute__((ext_vector_type(8)));
typedef float   f32x4  __attribute__((ext_vector_type(4)));

#define B_SZ   4
#define S_LEN  2048
#define D_DIM  1024
#define NH     16
#define DKH    64
#define M_ROWS (B_SZ * S_LEN)   // 8192

static __device__ __forceinline__ u16 f2bf(float f) {
  u32 x = __builtin_bit_cast(u32, f);
  return (u16)((x + 0x7fffu + ((x >> 16) & 1u)) >> 16);  // RNE
}

static __device__ __forceinline__ f32x4 mfma16(bf16x8 a, bf16x8 b, f32x4 c) {
  return __builtin_amdgcn_mfma_f32_16x16x32_bf16(a, b, c, 0, 0, 0);
}

static __device__ __forceinline__ void gld_lds16(const u16* g, u16* l) {
  __builtin_amdgcn_global_load_lds(
      (const __attribute__((address_space(1))) u32*)g,
      (__attribute__((address_space(3))) u32*)l, 16, 0, 0);
}

// ---------- f32 -> bf16 conversion, 4 elems/thread ----------
__global__ void k_cvt(const float* __restrict__ src, u16* __restrict__ dst, int n4) {
  int i = blockIdx.x * blockDim.x + threadIdx.x;
  if (i >= n4) return;
  float4 v = reinterpret_cast<const float4*>(src)[i];
  ushort4 o = { f2bf(v.x), f2bf(v.y), f2bf(v.z), f2bf(v.w) };
  reinterpret_cast<ushort4*>(dst)[i] = o;
}

// ---------- RoPE table: tab[s*32+k] = (cos, sin) of s * 10000^(-k/32) ----------
__global__ void k_table(float2* __restrict__ tab) {
  int i = blockIdx.x * blockDim.x + threadIdx.x;   // 65536 total
  int s = i >> 5, k = i & 31;
  float freq = powf(10000.0f, -(float)k / 32.0f);
  float a = (float)s * freq;
  tab[i] = make_float2(cosf(a), sinf(a));
}

// ---------- shared 128x128xK GEMM core: C = A(M0 tile) * W^T(N0 tile) ----------
// A: (8192 x 1024) bf16 row-major, W: (1024 x 1024) bf16 row-major (o,d).
static __device__ __forceinline__ void gemm_tile(
    const u16* __restrict__ A, const u16* __restrict__ W,
    int M0, int N0, u16* As, u16* Bs, f32x4 acc[4][4]) {
  int tid = threadIdx.x;
  int lane = tid & 63, wave = tid >> 6;
  int cl = lane & 15, gp = lane >> 4;
  int wr = wave >> 1, wc = wave & 1;
  for (int t = 0; t < 16; ++t) {
    int k0 = t * 64;
#pragma unroll
    for (int i = 0; i < 4; ++i) {
      int chunk = i * 4 + wave;              // 0..15, wave-uniform
      int rowA  = chunk * 8 + (lane >> 3);   // 0..127
      int col   = (lane & 7) * 8;            // 0..56
      gld_lds16(A + (size_t)(M0 + rowA) * D_DIM + k0 + col, As + chunk * 512);
      gld_lds16(W + (size_t)(N0 + rowA) * D_DIM + k0 + col, Bs + chunk * 512);
    }
    __syncthreads();
#pragma unroll
    for (int kk = 0; kk < 2; ++kk) {
      bf16x8 af[4], bfr[4];
#pragma unroll
      for (int m = 0; m < 4; ++m)
        af[m] = *reinterpret_cast<const bf16x8*>(As + (wr*64 + m*16 + cl)*64 + kk*32 + gp*8);
#pragma unroll
      for (int n = 0; n < 4; ++n)
        bfr[n] = *reinterpret_cast<const bf16x8*>(Bs + (wc*64 + n*16 + cl)*64 + kk*32 + gp*8);
#pragma unroll
      for (int m = 0; m < 4; ++m)
#pragma unroll
        for (int n = 0; n < 4; ++n)
          acc[m][n] = mfma16(af[m], bfr[n], acc[m][n]);
    }
    __syncthreads();
  }
}

// ---------- QKV projection + RoPE + layout ----------
// grid (64, 24): by>>3 selects proj (0=Q,1=K,2=V), by&7 selects 128-col strip.
// Q,K -> (b,h,s,dk) bf16 with RoPE. V -> (b,h,dk,s) bf16 (pre-transposed).
__global__ __launch_bounds__(256)
void k_gemm_qkv(const u16* __restrict__ Xb,
                const u16* __restrict__ Wqb, const u16* __restrict__ Wkb,
                const u16* __restrict__ Wvb,
                const float2* __restrict__ tab,
                u16* __restrict__ Qr, u16* __restrict__ Kr, u16* __restrict__ Vt) {
  __shared__ u16 As[128 * 64];
  __shared__ u16 Bs[128 * 64];
  int by   = blockIdx.y;
  int proj = by >> 3;
  int N0   = (by & 7) * 128;
  int M0   = blockIdx.x * 128;
  const u16* W = (proj == 0) ? Wqb : ((proj == 1) ? Wkb : Wvb);

  f32x4 zero = {0.f, 0.f, 0.f, 0.f};
  f32x4 acc[4][4];
#pragma unroll
  for (int m = 0; m < 4; ++m)
#pragma unroll
    for (int n = 0; n < 4; ++n) acc[m][n] = zero;

  gemm_tile(Xb, W, M0, N0, As, Bs, acc);

  int tid = threadIdx.x, lane = tid & 63, wave = tid >> 6;
  int cl = lane & 15, gp = lane >> 4;
  int wr = wave >> 1, wc = wave & 1;

  if (proj < 2) {
    u16* dst = (proj == 0) ? Qr : Kr;
#pragma unroll
    for (int m = 0; m < 4; ++m) {
#pragma unroll
      for (int n = 0; n < 4; ++n) {
        int colo = N0 + wc*64 + n*16 + cl;        // 0..1023
        int h = colo >> 6, dk = colo & 63;
        int kf = dk >> 1, par = dk & 1;
#pragma unroll
        for (int r = 0; r < 4; ++r) {
          int row = M0 + wr*64 + m*16 + gp*4 + r;  // global (b*S+s)
          int b = row >> 11, sp = row & (S_LEN - 1);
          float v = acc[m][n][r];
          float p = __shfl_xor(v, 1);              // partner column (2k<->2k+1)
          float2 cs = tab[sp * 32 + kf];
          float o = par ? (v * cs.x + p * cs.y) : (v * cs.x - p * cs.y);
          dst[((size_t)(b * NH + h) * S_LEN + sp) * DKH + dk] = f2bf(o);
        }
      }
    }
  } else {
#pragma unroll
    for (int m = 0; m < 4; ++m) {
#pragma unroll
      for (int n = 0; n < 4; ++n) {
        int colo = N0 + wc*64 + n*16 + cl;
        int h = colo >> 6, dk = colo & 63;
        int row0 = M0 + wr*64 + m*16 + gp*4;       // 4 consecutive s
        int b = row0 >> 11, sp0 = row0 & (S_LEN - 1);
        ushort4 o4 = { f2bf(acc[m][n][0]), f2bf(acc[m][n][1]),
                       f2bf(acc[m][n][2]), f2bf(acc[m][n][3]) };
        *reinterpret_cast<ushort4*>(
            Vt + ((size_t)(b * NH + h) * DKH + dk) * S_LEN + sp0) = o4;
      }
    }
  }
}

// ---------- flash attention, causal ----------
// grid (32, 64): x = q-block of 64 rows, y = b*16+h. 4 waves x 16 q-rows.
__global__ __launch_bounds__(256)
void k_attn(const u16* __restrict__ Q, const u16* __restrict__ K,
            const u16* __restrict__ Vt, u16* __restrict__ Ob) {
  __shared__ u16 Ks[64 * 72];     // (kv, dk) padded: 144B rows (9 bank-quads)
  __shared__ u16 Vs[64 * 72];     // (dk, kv) padded
  __shared__ u16 Ps[4][16 * 72];  // per-wave P staging, padded

  int tid = threadIdx.x, lane = tid & 63, w = tid >> 6;
  int cl = lane & 15, gp = lane >> 4;
  int bh = blockIdx.y;
  int q0 = blockIdx.x * 64;
  int qw = q0 + w * 16;
  const u16* Qb = Q  + (size_t)bh * S_LEN * DKH;
  const u16* Kb = K  + (size_t)bh * S_LEN * DKH;
  const u16* Vb = Vt + (size_t)bh * DKH * S_LEN;

  bf16x8 qf[2];
  {
    int qrow = qw + cl;
    qf[0] = *reinterpret_cast<const bf16x8*>(Qb + (size_t)qrow * DKH + gp * 8);
    qf[1] = *reinterpret_cast<const bf16x8*>(Qb + (size_t)qrow * DKH + 32 + gp * 8);
  }
  f32x4 zero = {0.f, 0.f, 0.f, 0.f};
  f32x4 o[4];
#pragma unroll
  for (int n = 0; n < 4; ++n) o[n] = zero;
  float mrow[4] = {-1e30f, -1e30f, -1e30f, -1e30f};
  float lrow[4] = {0.f, 0.f, 0.f, 0.f};

  int tmax = q0 >> 6;
  for (int t = 0; t <= tmax; ++t) {
    // stage K (kv,dk) and V^T (dk,kv) tiles, 16B per thread-slot
#pragma unroll
    for (int j = 0; j < 2; ++j) {
      int idx = tid + j * 256;
      int r = idx >> 3, c = (idx & 7) * 8;
      *reinterpret_cast<uint4*>(&Ks[r * 72 + c]) =
          *reinterpret_cast<const uint4*>(Kb + (size_t)(t * 64 + r) * DKH + c);
      *reinterpret_cast<uint4*>(&Vs[r * 72 + c]) =
          *reinterpret_cast<const uint4*>(Vb + (size_t)r * S_LEN + t * 64 + c);
    }
    __syncthreads();

    // S = Q * K^T
    f32x4 sf[4];
#pragma unroll
    for (int n = 0; n < 4; ++n) sf[n] = zero;
#pragma unroll
    for (int kk = 0; kk < 2; ++kk) {
#pragma unroll
      for (int n = 0; n < 4; ++n) {
        bf16x8 kf = *reinterpret_cast<const bf16x8*>(&Ks[(n*16 + cl)*72 + kk*32 + gp*8]);
        sf[n] = mfma16(qf[kk], kf, sf[n]);
      }
    }

    // online softmax (rows are (gp*4+r); cols are lanes cl within 16-group)
#pragma unroll
    for (int r = 0; r < 4; ++r) {
      int q = qw + gp * 4 + r;
      float mx = -1e30f;
#pragma unroll
      for (int n = 0; n < 4; ++n) {
        int kv = t * 64 + n * 16 + cl;
        float s = sf[n][r] * 0.125f;
        s = (kv <= q) ? s : -1e30f;
        sf[n][r] = s;
        mx = fmaxf(mx, s);
      }
      mx = fmaxf(mx, __shfl_xor(mx, 1));
      mx = fmaxf(mx, __shfl_xor(mx, 2));
      mx = fmaxf(mx, __shfl_xor(mx, 4));
      mx = fmaxf(mx, __shfl_xor(mx, 8));
      float mn = fmaxf(mrow[r], mx);
      float al = __expf(mrow[r] - mn);
      mrow[r] = mn;
      float rs = 0.f;
#pragma unroll
      for (int n = 0; n < 4; ++n) {
        float p = __expf(sf[n][r] - mn);
        rs += p;
        Ps[w][(gp*4 + r) * 72 + n*16 + cl] = f2bf(p);
      }
      rs += __shfl_xor(rs, 1);
      rs += __shfl_xor(rs, 2);
      rs += __shfl_xor(rs, 4);
      rs += __shfl_xor(rs, 8);
      lrow[r] = lrow[r] * al + rs;
#pragma unroll
      for (int n = 0; n < 4; ++n) o[n][r] *= al;
    }

    // O += P * V   (A = P from padded LDS, B = V via pre-transposed Vs)
#pragma unroll
    for (int kk = 0; kk < 2; ++kk) {
      bf16x8 pf = *reinterpret_cast<const bf16x8*>(&Ps[w][cl*72 + kk*32 + gp*8]);
#pragma unroll
      for (int n = 0; n < 4; ++n) {
        bf16x8 vf = *reinterpret_cast<const bf16x8*>(&Vs[(n*16 + cl)*72 + kk*32 + gp*8]);
        o[n] = mfma16(pf, vf, o[n]);
      }
    }
    __syncthreads();
  }

  int b = bh >> 4, h = bh & 15;
#pragma unroll
  for (int n = 0; n < 4; ++n) {
#pragma unroll
    for (int r = 0; r < 4; ++r) {
      int q = qw + gp * 4 + r;
      float val = o[n][r] / lrow[r];
      Ob[(size_t)(b * S_LEN + q) * D_DIM + h * DKH + n*16 + cl] = f2bf(val);
    }
  }
}

// ---------- output projection: out = attn * Wo^T, f32 stores ----------
__global__ __launch_bounds__(256)
void k_gemm_out(const u16* __restrict__ Ab, const u16* __restrict__ Wob,
                float* __restrict__ out) {
  __shared__ u16 As[128 * 64];
  __shared__ u16 Bs[128 * 64];
  int M0 = blockIdx.x * 128, N0 = blockIdx.y * 128;
  f32x4 zero = {0.f, 0.f, 0.f, 0.f};
  f32x4 acc[4][4];
#pragma unroll
  for (int m = 0; m < 4; ++m)
#pragma unroll
    for (int n = 0; n < 4; ++n) acc[m][n] = zero;

  gemm_tile(Ab, Wob, M0, N0, As, Bs, acc);

  int tid = threadIdx.x, lane = tid & 63, wave = tid >> 6;
  int cl = lane & 15, gp = lane >> 4;
  int wr = wave >> 1, wc = wave & 1;
#pragma unroll
  for (int m = 0; m < 4; ++m)
#pragma unroll
    for (int n = 0; n < 4; ++n)
#pragma unroll
      for (int r = 0; r < 4; ++r) {
        int row = M0 + wr*64 + m*16 + gp*4 + r;
        int col = N0 + wc*64 + n*16 + cl;
        out[(size_t)row * D_DIM + col] = acc[m][n][r];
      }
}

extern "C" void kernel_launch(void* const* d_in, const int* in_sizes, int n_in,
                              void* d_out, int out_size, void* d_ws, size_t ws_size,
                              hipStream_t stream) {
  const float* x  = (const float*)d_in[0];
  const float* Wq = (const float*)d_in[1];
  const float* Wk = (const float*)d_in[2];
  const float* Wv = (const float*)d_in[3];
  const float* Wo = (const float*)d_in[4];
  float* out = (float*)d_out;

  char* ws = (char*)d_ws;
  size_t off = 0;
  u16* xb  = (u16*)(ws + off); off += (size_t)M_ROWS * D_DIM * 2;   // 16 MB
  u16* wqb = (u16*)(ws + off); off += (size_t)D_DIM * D_DIM * 2;    // 2 MB
  u16* wkb = (u16*)(ws + off); off += (size_t)D_DIM * D_DIM * 2;
  u16* wvb = (u16*)(ws + off); off += (size_t)D_DIM * D_DIM * 2;
  u16* wob = (u16*)(ws + off); off += (size_t)D_DIM * D_DIM * 2;
  float2* tab = (float2*)(ws + off); off += (size_t)S_LEN * 32 * 8; // 0.5 MB
  u16* Qr = (u16*)(ws + off); off += (size_t)M_ROWS * D_DIM * 2;    // 16 MB
  u16* Kr = (u16*)(ws + off); off += (size_t)M_ROWS * D_DIM * 2;
  u16* Vt = (u16*)(ws + off); off += (size_t)M_ROWS * D_DIM * 2;
  u16* Ab = (u16*)(ws + off); off += (size_t)M_ROWS * D_DIM * 2;
  (void)ws_size; (void)in_sizes; (void)n_in; (void)out_size;

  k_cvt<<<8192, 256, 0, stream>>>(x,  xb,  (M_ROWS * D_DIM) / 4);
  k_cvt<<<1024, 256, 0, stream>>>(Wq, wqb, (D_DIM * D_DIM) / 4);
  k_cvt<<<1024, 256, 0, stream>>>(Wk, wkb, (D_DIM * D_DIM) / 4);
  k_cvt<<<1024, 256, 0, stream>>>(Wv, wvb, (D_DIM * D_DIM) / 4);
  k_cvt<<<1024, 256, 0, stream>>>(Wo, wob, (D_DIM * D_DIM) / 4);
  k_table<<<256, 256, 0, stream>>>(tab);

  k_gemm_qkv<<<dim3(64, 24), 256, 0, stream>>>(xb, wqb, wkb, wvb, tab, Qr, Kr, Vt);
  k_attn<<<dim3(32, 64), 256, 0, stream>>>(Qr, Kr, Vt, Ab);
  k_gemm_out<<<dim3(64, 8), 256, 0, stream>>>(Ab, wob, out);
}

// Round 2
// 260.064 us; speedup vs baseline: 1.3961x; 1.3961x over previous
//
#include <hip/hip_runtime.h>
#include <stdint.h>

typedef unsigned short u16;
typedef unsigned int   u32;
typedef __bf16  bf16x8 __attribute__((ext_vector_type(8)));
typedef float   f32x4  __attribute__((ext_vector_type(4)));

#define B_SZ   4
#define S_LEN  2048
#define D_DIM  1024
#define NH     16
#define DKH    64
#define M_ROWS (B_SZ * S_LEN)   // 8192

// softmax scale folded into exp2 domain: 1/sqrt(64) * log2(e)
#define C_SC 0.1803368801111204f

static __device__ __forceinline__ u16 f2bf(float f) {
  u32 x = __builtin_bit_cast(u32, f);
  return (u16)((x + 0x7fffu + ((x >> 16) & 1u)) >> 16);  // RNE
}

static __device__ __forceinline__ float fexp2(float x) {
  return __builtin_amdgcn_exp2f(x);
}

static __device__ __forceinline__ f32x4 mfma16(bf16x8 a, bf16x8 b, f32x4 c) {
  return __builtin_amdgcn_mfma_f32_16x16x32_bf16(a, b, c, 0, 0, 0);
}

static __device__ __forceinline__ void gld_lds16(const u16* g, u16* l) {
  __builtin_amdgcn_global_load_lds(
      (const __attribute__((address_space(1))) u32*)g,
      (__attribute__((address_space(3))) u32*)l, 16, 0, 0);
}

// workgroup barrier that drains LDS ops only — outstanding global loads
// (vmcnt) survive across it, enabling cross-barrier prefetch.
static __device__ __forceinline__ void wg_barrier() {
  asm volatile("s_waitcnt lgkmcnt(0)" ::: "memory");
  __builtin_amdgcn_s_barrier();
  __builtin_amdgcn_sched_barrier(0);
}

// XOR swizzle for row-major [R][64] u16 LDS tiles: balanced banks for
// b128 column-slice reads. Applied identically on write and read.
#define SWZ(row, col) (((row) * 64) + (((col) ^ (((row) & 7) << 3))))

// ---------- f32 -> bf16 conversion, 4 elems/thread ----------
__global__ void k_cvt(const float* __restrict__ src, u16* __restrict__ dst, int n4) {
  int i = blockIdx.x * blockDim.x + threadIdx.x;
  if (i >= n4) return;
  float4 v = reinterpret_cast<const float4*>(src)[i];
  ushort4 o = { f2bf(v.x), f2bf(v.y), f2bf(v.z), f2bf(v.w) };
  reinterpret_cast<ushort4*>(dst)[i] = o;
}

// ---------- RoPE table: tab[s*32+k] = (cos, sin) of s * 10000^(-k/32) ----------
__global__ void k_table(float2* __restrict__ tab) {
  int i = blockIdx.x * blockDim.x + threadIdx.x;   // 65536 total
  int s = i >> 5, k = i & 31;
  float freq = powf(10000.0f, -(float)k / 32.0f);
  float a = (float)s * freq;
  tab[i] = make_float2(cosf(a), sinf(a));
}

// ---------- shared 128x128xK GEMM core: C = A(M0 tile) * W^T(N0 tile) ----------
static __device__ __forceinline__ void gemm_tile(
    const u16* __restrict__ A, const u16* __restrict__ W,
    int M0, int N0, u16* As, u16* Bs, f32x4 acc[4][4]) {
  int tid = threadIdx.x;
  int lane = tid & 63, wave = tid >> 6;
  int cl = lane & 15, gp = lane >> 4;
  int wr = wave >> 1, wc = wave & 1;
  for (int t = 0; t < 16; ++t) {
    int k0 = t * 64;
#pragma unroll
    for (int i = 0; i < 4; ++i) {
      int chunk = i * 4 + wave;              // 0..15, wave-uniform
      int rowA  = chunk * 8 + (lane >> 3);   // 0..127
      int col   = (lane & 7) * 8;            // 0..56
      gld_lds16(A + (size_t)(M0 + rowA) * D_DIM + k0 + col, As + chunk * 512);
      gld_lds16(W + (size_t)(N0 + rowA) * D_DIM + k0 + col, Bs + chunk * 512);
    }
    __syncthreads();
#pragma unroll
    for (int kk = 0; kk < 2; ++kk) {
      bf16x8 af[4], bfr[4];
#pragma unroll
      for (int m = 0; m < 4; ++m)
        af[m] = *reinterpret_cast<const bf16x8*>(As + (wr*64 + m*16 + cl)*64 + kk*32 + gp*8);
#pragma unroll
      for (int n = 0; n < 4; ++n)
        bfr[n] = *reinterpret_cast<const bf16x8*>(Bs + (wc*64 + n*16 + cl)*64 + kk*32 + gp*8);
#pragma unroll
      for (int m = 0; m < 4; ++m)
#pragma unroll
        for (int n = 0; n < 4; ++n)
          acc[m][n] = mfma16(af[m], bfr[n], acc[m][n]);
    }
    __syncthreads();
  }
}

// ---------- QKV projection + RoPE + layout ----------
__global__ __launch_bounds__(256)
void k_gemm_qkv(const u16* __restrict__ Xb,
                const u16* __restrict__ Wqb, const u16* __restrict__ Wkb,
                const u16* __restrict__ Wvb,
                const float2* __restrict__ tab,
                u16* __restrict__ Qr, u16* __restrict__ Kr, u16* __restrict__ Vt) {
  __shared__ u16 As[128 * 64];
  __shared__ u16 Bs[128 * 64];
  int by   = blockIdx.y;
  int proj = by >> 3;
  int N0   = (by & 7) * 128;
  int M0   = blockIdx.x * 128;
  const u16* W = (proj == 0) ? Wqb : ((proj == 1) ? Wkb : Wvb);

  f32x4 zero = {0.f, 0.f, 0.f, 0.f};
  f32x4 acc[4][4];
#pragma unroll
  for (int m = 0; m < 4; ++m)
#pragma unroll
    for (int n = 0; n < 4; ++n) acc[m][n] = zero;

  gemm_tile(Xb, W, M0, N0, As, Bs, acc);

  int tid = threadIdx.x, lane = tid & 63, wave = tid >> 6;
  int cl = lane & 15, gp = lane >> 4;
  int wr = wave >> 1, wc = wave & 1;

  if (proj < 2) {
    u16* dst = (proj == 0) ? Qr : Kr;
#pragma unroll
    for (int m = 0; m < 4; ++m) {
#pragma unroll
      for (int n = 0; n < 4; ++n) {
        int colo = N0 + wc*64 + n*16 + cl;        // 0..1023
        int h = colo >> 6, dk = colo & 63;
        int kf = dk >> 1, par = dk & 1;
#pragma unroll
        for (int r = 0; r < 4; ++r) {
          int row = M0 + wr*64 + m*16 + gp*4 + r;  // global (b*S+s)
          int b = row >> 11, sp = row & (S_LEN - 1);
          float v = acc[m][n][r];
          float p = __shfl_xor(v, 1);              // partner column (2k<->2k+1)
          float2 cs = tab[sp * 32 + kf];
          float o = par ? (v * cs.x + p * cs.y) : (v * cs.x - p * cs.y);
          dst[((size_t)(b * NH + h) * S_LEN + sp) * DKH + dk] = f2bf(o);
        }
      }
    }
  } else {
#pragma unroll
    for (int m = 0; m < 4; ++m) {
#pragma unroll
      for (int n = 0; n < 4; ++n) {
        int colo = N0 + wc*64 + n*16 + cl;
        int h = colo >> 6, dk = colo & 63;
        int row0 = M0 + wr*64 + m*16 + gp*4;       // 4 consecutive s
        int b = row0 >> 11, sp0 = row0 & (S_LEN - 1);
        ushort4 o4 = { f2bf(acc[m][n][0]), f2bf(acc[m][n][1]),
                       f2bf(acc[m][n][2]), f2bf(acc[m][n][3]) };
        *reinterpret_cast<ushort4*>(
            Vt + ((size_t)(b * NH + h) * DKH + dk) * S_LEN + sp0) = o4;
      }
    }
  }
}

// ---------- flash attention, causal, triangle-paired ----------
// grid (16, 64): block x handles q-blocks {x, 31-x} of 64 rows for bh = y.
// 4 waves x 16 q-rows; KV tile 64; double-buffered swizzled LDS; 2-deep
// global prefetch surviving the (lgkm-only) barrier.
__global__ __launch_bounds__(256)
void k_attn(const u16* __restrict__ Q, const u16* __restrict__ K,
            const u16* __restrict__ Vt, u16* __restrict__ Ob) {
  __shared__ u16 Ks[2][64 * 64];
  __shared__ u16 Vs[2][64 * 64];
  __shared__ u16 Ps[4][16 * 64];

  const int tid = threadIdx.x, lane = tid & 63, w = tid >> 6;
  const int cl = lane & 15, gp = lane >> 4;
  const int bh = blockIdx.y;
  const int pair = blockIdx.x;               // 0..15
  const u16* Qb = Q  + (size_t)bh * S_LEN * DKH;
  const u16* Kb = K  + (size_t)bh * S_LEN * DKH;
  const u16* Vb = Vt + (size_t)bh * DKH * S_LEN;
  const int b = bh >> 4, h = bh & 15;

  // staging geometry: 2 x 16B per thread per matrix
  const int srow = tid >> 3;                 // 0..31
  const int scol = (tid & 7) * 8;            // 0..56
  const int so0 = SWZ(srow, scol);
  const int so1 = SWZ(srow + 32, scol);      // (srow+32)&7 == srow&7
  const u16* kg0 = Kb + (size_t)srow * DKH + scol;
  const u16* kg1 = Kb + (size_t)(srow + 32) * DKH + scol;
  const u16* vg0 = Vb + (size_t)srow * S_LEN + scol;
  const u16* vg1 = Vb + (size_t)(srow + 32) * S_LEN + scol;

  const f32x4 zero = {0.f, 0.f, 0.f, 0.f};

#pragma unroll 1
  for (int seg = 0; seg < 2; ++seg) {
    const int qb   = seg ? (31 - pair) : pair;
    const int tmax = qb;
    const int qw   = qb * 64 + w * 16;

    bf16x8 qf[2];
    {
      const u16* qp = Qb + (size_t)(qw + cl) * DKH + gp * 8;
      qf[0] = *reinterpret_cast<const bf16x8*>(qp);
      qf[1] = *reinterpret_cast<const bf16x8*>(qp + 32);
    }
    f32x4 o[4];
#pragma unroll
    for (int n = 0; n < 4; ++n) o[n] = zero;
    float mrow[4] = {-1e30f, -1e30f, -1e30f, -1e30f};
    float lrow[4] = {0.f, 0.f, 0.f, 0.f};

    // tile 0 loads
    uint4 kr0 = *reinterpret_cast<const uint4*>(kg0);
    uint4 kr1 = *reinterpret_cast<const uint4*>(kg1);
    uint4 vr0 = *reinterpret_cast<const uint4*>(vg0);
    uint4 vr1 = *reinterpret_cast<const uint4*>(vg1);

    wg_barrier();   // previous segment's LDS reads all complete
    *reinterpret_cast<uint4*>(&Ks[0][so0]) = kr0;
    *reinterpret_cast<uint4*>(&Ks[0][so1]) = kr1;
    *reinterpret_cast<uint4*>(&Vs[0][so0]) = vr0;
    *reinterpret_cast<uint4*>(&Vs[0][so1]) = vr1;
    if (tmax >= 1) {  // prefetch tile 1
      kr0 = *reinterpret_cast<const uint4*>(kg0 + 64 * DKH);
      kr1 = *reinterpret_cast<const uint4*>(kg1 + 64 * DKH);
      vr0 = *reinterpret_cast<const uint4*>(vg0 + 64);
      vr1 = *reinterpret_cast<const uint4*>(vg1 + 64);
    }

    int cur = 0;
#pragma unroll 1
    for (int t = 0; t <= tmax; ++t) {
      wg_barrier();   // buf[cur] (tile t) visible; vmcnt prefetch survives

      // ---- S = Q K^T (raw scores) ----
      f32x4 sf[4];
#pragma unroll
      for (int n = 0; n < 4; ++n) sf[n] = zero;
#pragma unroll
      for (int kk = 0; kk < 2; ++kk) {
#pragma unroll
        for (int n = 0; n < 4; ++n) {
          bf16x8 kf = *reinterpret_cast<const bf16x8*>(
              &Ks[cur][SWZ(n * 16 + cl, kk * 32 + gp * 8)]);
          sf[n] = mfma16(qf[kk], kf, sf[n]);
        }
      }

      // causal mask: only the diagonal tile needs it
      if (t == tmax) {
#pragma unroll
        for (int n = 0; n < 4; ++n) {
          int kvr = n * 16 + cl;
#pragma unroll
          for (int r = 0; r < 4; ++r)
            if (kvr > w * 16 + gp * 4 + r) sf[n][r] = -1e30f;
        }
      }

      // ---- online softmax (exp2 domain, scale folded) ----
#pragma unroll
      for (int r = 0; r < 4; ++r) {
        float mx = fmaxf(fmaxf(sf[0][r], sf[1][r]), fmaxf(sf[2][r], sf[3][r]));
        mx = fmaxf(mx, __shfl_xor(mx, 1));
        mx = fmaxf(mx, __shfl_xor(mx, 2));
        mx = fmaxf(mx, __shfl_xor(mx, 4));
        mx = fmaxf(mx, __shfl_xor(mx, 8));
        const float mn = fmaxf(mrow[r], mx);
        const float al = fexp2((mrow[r] - mn) * C_SC);
        mrow[r] = mn;
        float rs = 0.f;
        const int pr = gp * 4 + r;
#pragma unroll
        for (int n = 0; n < 4; ++n) {
          float p = fexp2((sf[n][r] - mn) * C_SC);
          rs += p;
          Ps[w][SWZ(pr, n * 16 + cl)] = f2bf(p);
        }
        rs += __shfl_xor(rs, 1);
        rs += __shfl_xor(rs, 2);
        rs += __shfl_xor(rs, 4);
        rs += __shfl_xor(rs, 8);
        lrow[r] = lrow[r] * al + rs;
        o[0][r] *= al; o[1][r] *= al; o[2][r] *= al; o[3][r] *= al;
      }

      // ---- stage tile t+1 into the other buffer; prefetch tile t+2 ----
      if (t < tmax) {
        *reinterpret_cast<uint4*>(&Ks[cur ^ 1][so0]) = kr0;
        *reinterpret_cast<uint4*>(&Ks[cur ^ 1][so1]) = kr1;
        *reinterpret_cast<uint4*>(&Vs[cur ^ 1][so0]) = vr0;
        *reinterpret_cast<uint4*>(&Vs[cur ^ 1][so1]) = vr1;
        if (t + 1 < tmax) {
          const size_t ko = (size_t)(t + 2) * 64 * DKH;
          const size_t vo = (size_t)(t + 2) * 64;
          kr0 = *reinterpret_cast<const uint4*>(kg0 + ko);
          kr1 = *reinterpret_cast<const uint4*>(kg1 + ko);
          vr0 = *reinterpret_cast<const uint4*>(vg0 + vo);
          vr1 = *reinterpret_cast<const uint4*>(vg1 + vo);
        }
      }

      // ---- O += P V ----
#pragma unroll
      for (int kk = 0; kk < 2; ++kk) {
        bf16x8 pf = *reinterpret_cast<const bf16x8*>(
            &Ps[w][SWZ(cl, kk * 32 + gp * 8)]);
#pragma unroll
        for (int n = 0; n < 4; ++n) {
          bf16x8 vf = *reinterpret_cast<const bf16x8*>(
              &Vs[cur][SWZ(n * 16 + cl, kk * 32 + gp * 8)]);
          o[n] = mfma16(pf, vf, o[n]);
        }
      }
      cur ^= 1;
    }

    // ---- epilogue ----
    float inv[4];
#pragma unroll
    for (int r = 0; r < 4; ++r) inv[r] = 1.0f / lrow[r];
#pragma unroll
    for (int n = 0; n < 4; ++n) {
#pragma unroll
      for (int r = 0; r < 4; ++r) {
        int q = qw + gp * 4 + r;
        Ob[(size_t)(b * S_LEN + q) * D_DIM + h * DKH + n * 16 + cl] =
            f2bf(o[n][r] * inv[r]);
      }
    }
  }
}

// ---------- output projection: out = attn * Wo^T, f32 stores ----------
__global__ __launch_bounds__(256)
void k_gemm_out(const u16* __restrict__ Ab, const u16* __restrict__ Wob,
                float* __restrict__ out) {
  __shared__ u16 As[128 * 64];
  __shared__ u16 Bs[128 * 64];
  int M0 = blockIdx.x * 128, N0 = blockIdx.y * 128;
  f32x4 zero = {0.f, 0.f, 0.f, 0.f};
  f32x4 acc[4][4];
#pragma unroll
  for (int m = 0; m < 4; ++m)
#pragma unroll
    for (int n = 0; n < 4; ++n) acc[m][n] = zero;

  gemm_tile(Ab, Wob, M0, N0, As, Bs, acc);

  int tid = threadIdx.x, lane = tid & 63, wave = tid >> 6;
  int cl = lane & 15, gp = lane >> 4;
  int wr = wave >> 1, wc = wave & 1;
#pragma unroll
  for (int m = 0; m < 4; ++m)
#pragma unroll
    for (int n = 0; n < 4; ++n)
#pragma unroll
      for (int r = 0; r < 4; ++r) {
        int row = M0 + wr*64 + m*16 + gp*4 + r;
        int col = N0 + wc*64 + n*16 + cl;
        out[(size_t)row * D_DIM + col] = acc[m][n][r];
      }
}

extern "C" void kernel_launch(void* const* d_in, const int* in_sizes, int n_in,
                              void* d_out, int out_size, void* d_ws, size_t ws_size,
                              hipStream_t stream) {
  const float* x  = (const float*)d_in[0];
  const float* Wq = (const float*)d_in[1];
  const float* Wk = (const float*)d_in[2];
  const float* Wv = (const float*)d_in[3];
  const float* Wo = (const float*)d_in[4];
  float* out = (float*)d_out;

  char* ws = (char*)d_ws;
  size_t off = 0;
  u16* xb  = (u16*)(ws + off); off += (size_t)M_ROWS * D_DIM * 2;   // 16 MB
  u16* wqb = (u16*)(ws + off); off += (size_t)D_DIM * D_DIM * 2;    // 2 MB
  u16* wkb = (u16*)(ws + off); off += (size_t)D_DIM * D_DIM * 2;
  u16* wvb = (u16*)(ws + off); off += (size_t)D_DIM * D_DIM * 2;
  u16* wob = (u16*)(ws + off); off += (size_t)D_DIM * D_DIM * 2;
  float2* tab = (float2*)(ws + off); off += (size_t)S_LEN * 32 * 8; // 0.5 MB
  u16* Qr = (u16*)(ws + off); off += (size_t)M_ROWS * D_DIM * 2;    // 16 MB
  u16* Kr = (u16*)(ws + off); off += (size_t)M_ROWS * D_DIM * 2;
  u16* Vt = (u16*)(ws + off); off += (size_t)M_ROWS * D_DIM * 2;
  u16* Ab = (u16*)(ws + off); off += (size_t)M_ROWS * D_DIM * 2;
  (void)ws_size; (void)in_sizes; (void)n_in; (void)out_size;

  k_cvt<<<8192, 256, 0, stream>>>(x,  xb,  (M_ROWS * D_DIM) / 4);
  k_cvt<<<1024, 256, 0, stream>>>(Wq, wqb, (D_DIM * D_DIM) / 4);
  k_cvt<<<1024, 256, 0, stream>>>(Wk, wkb, (D_DIM * D_DIM) / 4);
  k_cvt<<<1024, 256, 0, stream>>>(Wv, wvb, (D_DIM * D_DIM) / 4);
  k_cvt<<<1024, 256, 0, stream>>>(Wo, wob, (D_DIM * D_DIM) / 4);
  k_table<<<256, 256, 0, stream>>>(tab);

  k_gemm_qkv<<<dim3(64, 24), 256, 0, stream>>>(xb, wqb, wkb, wvb, tab, Qr, Kr, Vt);
  k_attn<<<dim3(16, 64), 256, 0, stream>>>(Qr, Kr, Vt, Ab);
  k_gemm_out<<<dim3(64, 8), 256, 0, stream>>>(Ab, wob, out);
}

// Round 3
// 254.994 us; speedup vs baseline: 1.4238x; 1.0199x over previous
//
#include <hip/hip_runtime.h>
#include <stdint.h>

typedef unsigned short u16;
typedef unsigned int   u32;
typedef __bf16  bf16x8 __attribute__((ext_vector_type(8)));
typedef float   f32x4  __attribute__((ext_vector_type(4)));

#define B_SZ   4
#define S_LEN  2048
#define D_DIM  1024
#define NH     16
#define DKH    64
#define M_ROWS (B_SZ * S_LEN)   // 8192

// softmax scale folded into exp2 domain: 1/sqrt(64) * log2(e)
#define C_SC 0.1803368801111204f
// defer-max threshold in raw-score units: 8 / C_SC  (P bounded by 2^8)
#define DEFER_THR 44.36f

static __device__ __forceinline__ u16 f2bf(float f) {
  return __builtin_bit_cast(u16, (__bf16)f);   // hw v_cvt_pk_bf16_f32 (RNE)
}

static __device__ __forceinline__ float fexp2(float x) {
  return __builtin_amdgcn_exp2f(x);
}

static __device__ __forceinline__ f32x4 mfma16(bf16x8 a, bf16x8 b, f32x4 c) {
  return __builtin_amdgcn_mfma_f32_16x16x32_bf16(a, b, c, 0, 0, 0);
}

static __device__ __forceinline__ void gld_lds16(const u16* g, u16* l) {
  __builtin_amdgcn_global_load_lds(
      (const __attribute__((address_space(1))) u32*)g,
      (__attribute__((address_space(3))) u32*)l, 16, 0, 0);
}

// workgroup barrier that drains LDS ops only — outstanding global loads
// (vmcnt) survive across it, enabling cross-barrier prefetch.
static __device__ __forceinline__ void wg_barrier() {
  asm volatile("s_waitcnt lgkmcnt(0)" ::: "memory");
  __builtin_amdgcn_s_barrier();
  __builtin_amdgcn_sched_barrier(0);
}

// XOR swizzle for row-major [R][64] u16 LDS tiles: balanced banks for
// b128 column-slice reads. Applied identically on write and read.
#define SWZ(row, col) (((row) * 64) + (((col) ^ (((row) & 7) << 3))))

// ---------- f32 -> bf16 conversion, 4 elems/thread ----------
__global__ void k_cvt(const float* __restrict__ src, u16* __restrict__ dst, int n4) {
  int i = blockIdx.x * blockDim.x + threadIdx.x;
  if (i >= n4) return;
  float4 v = reinterpret_cast<const float4*>(src)[i];
  ushort4 o = { f2bf(v.x), f2bf(v.y), f2bf(v.z), f2bf(v.w) };
  reinterpret_cast<ushort4*>(dst)[i] = o;
}

// ---------- RoPE table: tab[s*32+k] = (cos, sin) of s * 10000^(-k/32) ----------
__global__ void k_table(float2* __restrict__ tab) {
  int i = blockIdx.x * blockDim.x + threadIdx.x;   // 65536 total
  int s = i >> 5, k = i & 31;
  float freq = powf(10000.0f, -(float)k / 32.0f);
  float a = (float)s * freq;
  tab[i] = make_float2(cosf(a), sinf(a));
}

// ---------- shared 128x128xK GEMM core: C = A(M0 tile) * W^T(N0 tile) ----------
static __device__ __forceinline__ void gemm_tile(
    const u16* __restrict__ A, const u16* __restrict__ W,
    int M0, int N0, u16* As, u16* Bs, f32x4 acc[4][4]) {
  int tid = threadIdx.x;
  int lane = tid & 63, wave = tid >> 6;
  int cl = lane & 15, gp = lane >> 4;
  int wr = wave >> 1, wc = wave & 1;
  for (int t = 0; t < 16; ++t) {
    int k0 = t * 64;
#pragma unroll
    for (int i = 0; i < 4; ++i) {
      int chunk = i * 4 + wave;              // 0..15, wave-uniform
      int rowA  = chunk * 8 + (lane >> 3);   // 0..127
      int col   = (lane & 7) * 8;            // 0..56
      gld_lds16(A + (size_t)(M0 + rowA) * D_DIM + k0 + col, As + chunk * 512);
      gld_lds16(W + (size_t)(N0 + rowA) * D_DIM + k0 + col, Bs + chunk * 512);
    }
    __syncthreads();
#pragma unroll
    for (int kk = 0; kk < 2; ++kk) {
      bf16x8 af[4], bfr[4];
#pragma unroll
      for (int m = 0; m < 4; ++m)
        af[m] = *reinterpret_cast<const bf16x8*>(As + (wr*64 + m*16 + cl)*64 + kk*32 + gp*8);
#pragma unroll
      for (int n = 0; n < 4; ++n)
        bfr[n] = *reinterpret_cast<const bf16x8*>(Bs + (wc*64 + n*16 + cl)*64 + kk*32 + gp*8);
#pragma unroll
      for (int m = 0; m < 4; ++m)
#pragma unroll
        for (int n = 0; n < 4; ++n)
          acc[m][n] = mfma16(af[m], bfr[n], acc[m][n]);
    }
    __syncthreads();
  }
}

// ---------- QKV projection + RoPE + layout ----------
__global__ __launch_bounds__(256)
void k_gemm_qkv(const u16* __restrict__ Xb,
                const u16* __restrict__ Wqb, const u16* __restrict__ Wkb,
                const u16* __restrict__ Wvb,
                const float2* __restrict__ tab,
                u16* __restrict__ Qr, u16* __restrict__ Kr, u16* __restrict__ Vt) {
  __shared__ u16 As[128 * 64];
  __shared__ u16 Bs[128 * 64];
  int by   = blockIdx.y;
  int proj = by >> 3;
  int N0   = (by & 7) * 128;
  int M0   = blockIdx.x * 128;
  const u16* W = (proj == 0) ? Wqb : ((proj == 1) ? Wkb : Wvb);

  f32x4 zero = {0.f, 0.f, 0.f, 0.f};
  f32x4 acc[4][4];
#pragma unroll
  for (int m = 0; m < 4; ++m)
#pragma unroll
    for (int n = 0; n < 4; ++n) acc[m][n] = zero;

  gemm_tile(Xb, W, M0, N0, As, Bs, acc);

  int tid = threadIdx.x, lane = tid & 63, wave = tid >> 6;
  int cl = lane & 15, gp = lane >> 4;
  int wr = wave >> 1, wc = wave & 1;

  if (proj < 2) {
    u16* dst = (proj == 0) ? Qr : Kr;
#pragma unroll
    for (int m = 0; m < 4; ++m) {
#pragma unroll
      for (int n = 0; n < 4; ++n) {
        int colo = N0 + wc*64 + n*16 + cl;        // 0..1023
        int h = colo >> 6, dk = colo & 63;
        int kf = dk >> 1, par = dk & 1;
#pragma unroll
        for (int r = 0; r < 4; ++r) {
          int row = M0 + wr*64 + m*16 + gp*4 + r;  // global (b*S+s)
          int b = row >> 11, sp = row & (S_LEN - 1);
          float v = acc[m][n][r];
          float p = __shfl_xor(v, 1);              // partner column (2k<->2k+1)
          float2 cs = tab[sp * 32 + kf];
          float o = par ? (v * cs.x + p * cs.y) : (v * cs.x - p * cs.y);
          dst[((size_t)(b * NH + h) * S_LEN + sp) * DKH + dk] = f2bf(o);
        }
      }
    }
  } else {
#pragma unroll
    for (int m = 0; m < 4; ++m) {
#pragma unroll
      for (int n = 0; n < 4; ++n) {
        int colo = N0 + wc*64 + n*16 + cl;
        int h = colo >> 6, dk = colo & 63;
        int row0 = M0 + wr*64 + m*16 + gp*4;       // 4 consecutive s
        int b = row0 >> 11, sp0 = row0 & (S_LEN - 1);
        ushort4 o4 = { f2bf(acc[m][n][0]), f2bf(acc[m][n][1]),
                       f2bf(acc[m][n][2]), f2bf(acc[m][n][3]) };
        *reinterpret_cast<ushort4*>(
            Vt + ((size_t)(b * NH + h) * DKH + dk) * S_LEN + sp0) = o4;
      }
    }
  }
}

// ---------- flash attention, causal, triangle-paired ----------
// grid (16, 64): block x handles q-blocks {x, 31-x} of 64 rows for bh = y.
// 4 waves x 16 q-rows; KV tile 64; double-buffered swizzled LDS; 2-deep
// global prefetch surviving the (lgkm-only) barrier. Softmax: deferred
// per-lane row-sum, defer-max rescale (T13), hw bf16 cvt, setprio MFMA.
__global__ __launch_bounds__(256)
void k_attn(const u16* __restrict__ Q, const u16* __restrict__ K,
            const u16* __restrict__ Vt, u16* __restrict__ Ob) {
  __shared__ u16 Ks[2][64 * 64];
  __shared__ u16 Vs[2][64 * 64];
  __shared__ u16 Ps[4][16 * 64];

  const int tid = threadIdx.x, lane = tid & 63, w = tid >> 6;
  const int cl = lane & 15, gp = lane >> 4;
  const int bh = blockIdx.y;
  const int pair = blockIdx.x;               // 0..15
  const u16* Qb = Q  + (size_t)bh * S_LEN * DKH;
  const u16* Kb = K  + (size_t)bh * S_LEN * DKH;
  const u16* Vb = Vt + (size_t)bh * DKH * S_LEN;
  const int b = bh >> 4, h = bh & 15;

  // staging geometry: 2 x 16B per thread per matrix
  const int srow = tid >> 3;                 // 0..31
  const int scol = (tid & 7) * 8;            // 0..56
  const int so0 = SWZ(srow, scol);
  const int so1 = SWZ(srow + 32, scol);      // (srow+32)&7 == srow&7
  const u16* kg0 = Kb + (size_t)srow * DKH + scol;
  const u16* kg1 = Kb + (size_t)(srow + 32) * DKH + scol;
  const u16* vg0 = Vb + (size_t)srow * S_LEN + scol;
  const u16* vg1 = Vb + (size_t)(srow + 32) * S_LEN + scol;

  const f32x4 zero = {0.f, 0.f, 0.f, 0.f};

#pragma unroll 1
  for (int seg = 0; seg < 2; ++seg) {
    const int qb   = seg ? (31 - pair) : pair;
    const int tmax = qb;
    const int qw   = qb * 64 + w * 16;

    bf16x8 qf[2];
    {
      const u16* qp = Qb + (size_t)(qw + cl) * DKH + gp * 8;
      qf[0] = *reinterpret_cast<const bf16x8*>(qp);
      qf[1] = *reinterpret_cast<const bf16x8*>(qp + 32);
    }
    f32x4 o[4];
#pragma unroll
    for (int n = 0; n < 4; ++n) o[n] = zero;
    float mrow[4] = {-1e30f, -1e30f, -1e30f, -1e30f};
    float plr[4]  = {0.f, 0.f, 0.f, 0.f};    // per-lane partial row sums

    // tile 0 loads
    uint4 kr0 = *reinterpret_cast<const uint4*>(kg0);
    uint4 kr1 = *reinterpret_cast<const uint4*>(kg1);
    uint4 vr0 = *reinterpret_cast<const uint4*>(vg0);
    uint4 vr1 = *reinterpret_cast<const uint4*>(vg1);

    wg_barrier();   // previous segment's LDS reads all complete
    *reinterpret_cast<uint4*>(&Ks[0][so0]) = kr0;
    *reinterpret_cast<uint4*>(&Ks[0][so1]) = kr1;
    *reinterpret_cast<uint4*>(&Vs[0][so0]) = vr0;
    *reinterpret_cast<uint4*>(&Vs[0][so1]) = vr1;
    if (tmax >= 1) {  // prefetch tile 1
      kr0 = *reinterpret_cast<const uint4*>(kg0 + 64 * DKH);
      kr1 = *reinterpret_cast<const uint4*>(kg1 + 64 * DKH);
      vr0 = *reinterpret_cast<const uint4*>(vg0 + 64);
      vr1 = *reinterpret_cast<const uint4*>(vg1 + 64);
    }

    int cur = 0;
#pragma unroll 1
    for (int t = 0; t <= tmax; ++t) {
      wg_barrier();   // buf[cur] (tile t) visible; vmcnt prefetch survives

      // ---- S = Q K^T (raw scores) ----
      f32x4 sf[4];
#pragma unroll
      for (int n = 0; n < 4; ++n) sf[n] = zero;
      __builtin_amdgcn_s_setprio(1);
#pragma unroll
      for (int kk = 0; kk < 2; ++kk) {
#pragma unroll
        for (int n = 0; n < 4; ++n) {
          bf16x8 kf = *reinterpret_cast<const bf16x8*>(
              &Ks[cur][SWZ(n * 16 + cl, kk * 32 + gp * 8)]);
          sf[n] = mfma16(qf[kk], kf, sf[n]);
        }
      }
      __builtin_amdgcn_s_setprio(0);

      // causal mask: only the diagonal tile needs it
      if (t == tmax) {
#pragma unroll
        for (int n = 0; n < 4; ++n) {
          int kvr = n * 16 + cl;
#pragma unroll
          for (int r = 0; r < 4; ++r)
            if (kvr > w * 16 + gp * 4 + r) sf[n][r] = -1e30f;
        }
      }

      // ---- online softmax (exp2 domain; deferred sum; defer-max) ----
#pragma unroll
      for (int r = 0; r < 4; ++r) {
        float mx = fmaxf(fmaxf(sf[0][r], sf[1][r]), fmaxf(sf[2][r], sf[3][r]));
        mx = fmaxf(mx, __shfl_xor(mx, 1));
        mx = fmaxf(mx, __shfl_xor(mx, 2));
        mx = fmaxf(mx, __shfl_xor(mx, 4));
        mx = fmaxf(mx, __shfl_xor(mx, 8));
        if (!__all(mx - mrow[r] <= DEFER_THR)) {   // rescale (rare after t0)
          const float mn = fmaxf(mrow[r], mx);
          const float al = fexp2((mrow[r] - mn) * C_SC);
          mrow[r] = mn;
          plr[r] *= al;
          o[0][r] *= al; o[1][r] *= al; o[2][r] *= al; o[3][r] *= al;
        }
        const float mnC = mrow[r] * C_SC;
        const int pr = gp * 4 + r;
        float p0 = fexp2(fmaf(sf[0][r], C_SC, -mnC));
        float p1 = fexp2(fmaf(sf[1][r], C_SC, -mnC));
        float p2 = fexp2(fmaf(sf[2][r], C_SC, -mnC));
        float p3 = fexp2(fmaf(sf[3][r], C_SC, -mnC));
        plr[r] += (p0 + p1) + (p2 + p3);
        *(__bf16*)&Ps[w][SWZ(pr, 0 * 16 + cl)] = (__bf16)p0;
        *(__bf16*)&Ps[w][SWZ(pr, 1 * 16 + cl)] = (__bf16)p1;
        *(__bf16*)&Ps[w][SWZ(pr, 2 * 16 + cl)] = (__bf16)p2;
        *(__bf16*)&Ps[w][SWZ(pr, 3 * 16 + cl)] = (__bf16)p3;
      }

      // ---- stage tile t+1 into the other buffer; prefetch tile t+2 ----
      if (t < tmax) {
        *reinterpret_cast<uint4*>(&Ks[cur ^ 1][so0]) = kr0;
        *reinterpret_cast<uint4*>(&Ks[cur ^ 1][so1]) = kr1;
        *reinterpret_cast<uint4*>(&Vs[cur ^ 1][so0]) = vr0;
        *reinterpret_cast<uint4*>(&Vs[cur ^ 1][so1]) = vr1;
        if (t + 1 < tmax) {
          const size_t ko = (size_t)(t + 2) * 64 * DKH;
          const size_t vo = (size_t)(t + 2) * 64;
          kr0 = *reinterpret_cast<const uint4*>(kg0 + ko);
          kr1 = *reinterpret_cast<const uint4*>(kg1 + ko);
          vr0 = *reinterpret_cast<const uint4*>(vg0 + vo);
          vr1 = *reinterpret_cast<const uint4*>(vg1 + vo);
        }
      }

      // ---- O += P V ----
      __builtin_amdgcn_s_setprio(1);
#pragma unroll
      for (int kk = 0; kk < 2; ++kk) {
        bf16x8 pf = *reinterpret_cast<const bf16x8*>(
            &Ps[w][SWZ(cl, kk * 32 + gp * 8)]);
#pragma unroll
        for (int n = 0; n < 4; ++n) {
          bf16x8 vf = *reinterpret_cast<const bf16x8*>(
              &Vs[cur][SWZ(n * 16 + cl, kk * 32 + gp * 8)]);
          o[n] = mfma16(pf, vf, o[n]);
        }
      }
      __builtin_amdgcn_s_setprio(0);
      cur ^= 1;
    }

    // ---- epilogue: reduce deferred row sums, normalize, store ----
    float inv[4];
#pragma unroll
    for (int r = 0; r < 4; ++r) {
      float rs = plr[r];
      rs += __shfl_xor(rs, 1);
      rs += __shfl_xor(rs, 2);
      rs += __shfl_xor(rs, 4);
      rs += __shfl_xor(rs, 8);
      inv[r] = 1.0f / rs;
    }
#pragma unroll
    for (int n = 0; n < 4; ++n) {
#pragma unroll
      for (int r = 0; r < 4; ++r) {
        int q = qw + gp * 4 + r;
        Ob[(size_t)(b * S_LEN + q) * D_DIM + h * DKH + n * 16 + cl] =
            f2bf(o[n][r] * inv[r]);
      }
    }
  }
}

// ---------- output projection: out = attn * Wo^T, f32 stores ----------
__global__ __launch_bounds__(256)
void k_gemm_out(const u16* __restrict__ Ab, const u16* __restrict__ Wob,
                float* __restrict__ out) {
  __shared__ u16 As[128 * 64];
  __shared__ u16 Bs[128 * 64];
  int M0 = blockIdx.x * 128, N0 = blockIdx.y * 128;
  f32x4 zero = {0.f, 0.f, 0.f, 0.f};
  f32x4 acc[4][4];
#pragma unroll
  for (int m = 0; m < 4; ++m)
#pragma unroll
    for (int n = 0; n < 4; ++n) acc[m][n] = zero;

  gemm_tile(Ab, Wob, M0, N0, As, Bs, acc);

  int tid = threadIdx.x, lane = tid & 63, wave = tid >> 6;
  int cl = lane & 15, gp = lane >> 4;
  int wr = wave >> 1, wc = wave & 1;
#pragma unroll
  for (int m = 0; m < 4; ++m)
#pragma unroll
    for (int n = 0; n < 4; ++n)
#pragma unroll
      for (int r = 0; r < 4; ++r) {
        int row = M0 + wr*64 + m*16 + gp*4 + r;
        int col = N0 + wc*64 + n*16 + cl;
        out[(size_t)row * D_DIM + col] = acc[m][n][r];
      }
}

extern "C" void kernel_launch(void* const* d_in, const int* in_sizes, int n_in,
                              void* d_out, int out_size, void* d_ws, size_t ws_size,
                              hipStream_t stream) {
  const float* x  = (const float*)d_in[0];
  const float* Wq = (const float*)d_in[1];
  const float* Wk = (const float*)d_in[2];
  const float* Wv = (const float*)d_in[3];
  const float* Wo = (const float*)d_in[4];
  float* out = (float*)d_out;

  char* ws = (char*)d_ws;
  size_t off = 0;
  u16* xb  = (u16*)(ws + off); off += (size_t)M_ROWS * D_DIM * 2;   // 16 MB
  u16* wqb = (u16*)(ws + off); off += (size_t)D_DIM * D_DIM * 2;    // 2 MB
  u16* wkb = (u16*)(ws + off); off += (size_t)D_DIM * D_DIM * 2;
  u16* wvb = (u16*)(ws + off); off += (size_t)D_DIM * D_DIM * 2;
  u16* wob = (u16*)(ws + off); off += (size_t)D_DIM * D_DIM * 2;
  float2* tab = (float2*)(ws + off); off += (size_t)S_LEN * 32 * 8; // 0.5 MB
  u16* Qr = (u16*)(ws + off); off += (size_t)M_ROWS * D_DIM * 2;    // 16 MB
  u16* Kr = (u16*)(ws + off); off += (size_t)M_ROWS * D_DIM * 2;
  u16* Vt = (u16*)(ws + off); off += (size_t)M_ROWS * D_DIM * 2;
  u16* Ab = (u16*)(ws + off); off += (size_t)M_ROWS * D_DIM * 2;
  (void)ws_size; (void)in_sizes; (void)n_in; (void)out_size;

  k_cvt<<<8192, 256, 0, stream>>>(x,  xb,  (M_ROWS * D_DIM) / 4);
  k_cvt<<<1024, 256, 0, stream>>>(Wq, wqb, (D_DIM * D_DIM) / 4);
  k_cvt<<<1024, 256, 0, stream>>>(Wk, wkb, (D_DIM * D_DIM) / 4);
  k_cvt<<<1024, 256, 0, stream>>>(Wv, wvb, (D_DIM * D_DIM) / 4);
  k_cvt<<<1024, 256, 0, stream>>>(Wo, wob, (D_DIM * D_DIM) / 4);
  k_table<<<256, 256, 0, stream>>>(tab);

  k_gemm_qkv<<<dim3(64, 24), 256, 0, stream>>>(xb, wqb, wkb, wvb, tab, Qr, Kr, Vt);
  k_attn<<<dim3(16, 64), 256, 0, stream>>>(Qr, Kr, Vt, Ab);
  k_gemm_out<<<dim3(64, 8), 256, 0, stream>>>(Ab, wob, out);
}

// Round 5
// 245.635 us; speedup vs baseline: 1.4781x; 1.0381x over previous
//
#include <hip/hip_runtime.h>
#include <stdint.h>

typedef unsigned short u16;
typedef unsigned int   u32;
typedef __bf16  bf16x8 __attribute__((ext_vector_type(8)));
typedef float   f32x4  __attribute__((ext_vector_type(4)));
typedef float   f32x16 __attribute__((ext_vector_type(16)));
typedef unsigned int u32x4 __attribute__((ext_vector_type(4)));

#define B_SZ   4
#define S_LEN  2048
#define D_DIM  1024
#define NH     16
#define DKH    64
#define M_ROWS (B_SZ * S_LEN)   // 8192

// softmax scale folded into exp2 domain: 1/sqrt(64) * log2(e)
#define C_SC 0.1803368801111204f
// defer-max threshold in raw-score units: 8 / C_SC  (P bounded by 2^8)
#define DEFER_THR 44.36f

// kv/q row owned by (reg r, lane-half hf) in a 32x32 MFMA C/D fragment
#define KVLOC(r, hf) ((((r) & 3)) + 8 * ((r) >> 2) + 4 * (hf))

static __device__ __forceinline__ u16 f2bf(float f) {
  return __builtin_bit_cast(u16, (__bf16)f);
}

// pack two f32 -> dword of 2 bf16, element0 in low bits (compiler-generated)
static __device__ __forceinline__ u32 pk2(float lo, float hi) {
  ushort2 u = { f2bf(lo), f2bf(hi) };
  return __builtin_bit_cast(u32, u);
}

static __device__ __forceinline__ float fexp2(float x) {
  return __builtin_amdgcn_exp2f(x);
}

static __device__ __forceinline__ f32x4 mfma16(bf16x8 a, bf16x8 b, f32x4 c) {
  return __builtin_amdgcn_mfma_f32_16x16x32_bf16(a, b, c, 0, 0, 0);
}

static __device__ __forceinline__ f32x16 mfma32(bf16x8 a, bf16x8 b, f32x16 c) {
  return __builtin_amdgcn_mfma_f32_32x32x16_bf16(a, b, c, 0, 0, 0);
}

static __device__ __forceinline__ void gld_lds16(const u16* g, u16* l) {
  __builtin_amdgcn_global_load_lds(
      (const __attribute__((address_space(1))) u32*)g,
      (__attribute__((address_space(3))) u32*)l, 16, 0, 0);
}

// workgroup barrier that drains LDS ops only — outstanding global loads
// (vmcnt) survive across it, enabling cross-barrier prefetch.
static __device__ __forceinline__ void wg_barrier() {
  asm volatile("s_waitcnt lgkmcnt(0)" ::: "memory");
  __builtin_amdgcn_s_barrier();
  __builtin_amdgcn_sched_barrier(0);
}

// XOR swizzle for row-major [R][64] u16 LDS tiles: even bank spread for
// b128 column-slice reads. Applied identically on write and read.
#define SWZ(row, col) (((row) * 64) + (((col) ^ (((row) & 7) << 3))))

// ---------- f32 -> bf16 conversion, 4 elems/thread ----------
__global__ void k_cvt(const float* __restrict__ src, u16* __restrict__ dst, int n4) {
  int i = blockIdx.x * blockDim.x + threadIdx.x;
  if (i >= n4) return;
  float4 v = reinterpret_cast<const float4*>(src)[i];
  ushort4 o = { f2bf(v.x), f2bf(v.y), f2bf(v.z), f2bf(v.w) };
  reinterpret_cast<ushort4*>(dst)[i] = o;
}

// ---------- RoPE table: tab[s*32+k] = (cos, sin) of s * 10000^(-k/32) ----------
__global__ void k_table(float2* __restrict__ tab) {
  int i = blockIdx.x * blockDim.x + threadIdx.x;   // 65536 total
  int s = i >> 5, k = i & 31;
  float freq = powf(10000.0f, -(float)k / 32.0f);
  float a = (float)s * freq;
  tab[i] = make_float2(cosf(a), sinf(a));
}

// ---------- shared 128x128xK GEMM core: C = A(M0 tile) * W^T(N0 tile) ----------
static __device__ __forceinline__ void gemm_tile(
    const u16* __restrict__ A, const u16* __restrict__ W,
    int M0, int N0, u16* As, u16* Bs, f32x4 acc[4][4]) {
  int tid = threadIdx.x;
  int lane = tid & 63, wave = tid >> 6;
  int cl = lane & 15, gp = lane >> 4;
  int wr = wave >> 1, wc = wave & 1;
  for (int t = 0; t < 16; ++t) {
    int k0 = t * 64;
#pragma unroll
    for (int i = 0; i < 4; ++i) {
      int chunk = i * 4 + wave;              // 0..15, wave-uniform
      int rowA  = chunk * 8 + (lane >> 3);   // 0..127
      int col   = (lane & 7) * 8;            // 0..56
      gld_lds16(A + (size_t)(M0 + rowA) * D_DIM + k0 + col, As + chunk * 512);
      gld_lds16(W + (size_t)(N0 + rowA) * D_DIM + k0 + col, Bs + chunk * 512);
    }
    __syncthreads();
#pragma unroll
    for (int kk = 0; kk < 2; ++kk) {
      bf16x8 af[4], bfr[4];
#pragma unroll
      for (int m = 0; m < 4; ++m)
        af[m] = *reinterpret_cast<const bf16x8*>(As + (wr*64 + m*16 + cl)*64 + kk*32 + gp*8);
#pragma unroll
      for (int n = 0; n < 4; ++n)
        bfr[n] = *reinterpret_cast<const bf16x8*>(Bs + (wc*64 + n*16 + cl)*64 + kk*32 + gp*8);
#pragma unroll
      for (int m = 0; m < 4; ++m)
#pragma unroll
        for (int n = 0; n < 4; ++n)
          acc[m][n] = mfma16(af[m], bfr[n], acc[m][n]);
    }
    __syncthreads();
  }
}

// ---------- QKV projection + RoPE + layout ----------
__global__ __launch_bounds__(256)
void k_gemm_qkv(const u16* __restrict__ Xb,
                const u16* __restrict__ Wqb, const u16* __restrict__ Wkb,
                const u16* __restrict__ Wvb,
                const float2* __restrict__ tab,
                u16* __restrict__ Qr, u16* __restrict__ Kr, u16* __restrict__ Vt) {
  __shared__ u16 As[128 * 64];
  __shared__ u16 Bs[128 * 64];
  int by   = blockIdx.y;
  int proj = by >> 3;
  int N0   = (by & 7) * 128;
  int M0   = blockIdx.x * 128;
  const u16* W = (proj == 0) ? Wqb : ((proj == 1) ? Wkb : Wvb);

  f32x4 zero = {0.f, 0.f, 0.f, 0.f};
  f32x4 acc[4][4];
#pragma unroll
  for (int m = 0; m < 4; ++m)
#pragma unroll
    for (int n = 0; n < 4; ++n) acc[m][n] = zero;

  gemm_tile(Xb, W, M0, N0, As, Bs, acc);

  int tid = threadIdx.x, lane = tid & 63, wave = tid >> 6;
  int cl = lane & 15, gp = lane >> 4;
  int wr = wave >> 1, wc = wave & 1;

  if (proj < 2) {
    u16* dst = (proj == 0) ? Qr : Kr;
#pragma unroll
    for (int m = 0; m < 4; ++m) {
#pragma unroll
      for (int n = 0; n < 4; ++n) {
        int colo = N0 + wc*64 + n*16 + cl;        // 0..1023
        int h = colo >> 6, dk = colo & 63;
        int kf = dk >> 1, par = dk & 1;
#pragma unroll
        for (int r = 0; r < 4; ++r) {
          int row = M0 + wr*64 + m*16 + gp*4 + r;  // global (b*S+s)
          int b = row >> 11, sp = row & (S_LEN - 1);
          float v = acc[m][n][r];
          float p = __shfl_xor(v, 1);              // partner column (2k<->2k+1)
          float2 cs = tab[sp * 32 + kf];
          float o = par ? (v * cs.x + p * cs.y) : (v * cs.x - p * cs.y);
          dst[((size_t)(b * NH + h) * S_LEN + sp) * DKH + dk] = f2bf(o);
        }
      }
    }
  } else {
#pragma unroll
    for (int m = 0; m < 4; ++m) {
#pragma unroll
      for (int n = 0; n < 4; ++n) {
        int colo = N0 + wc*64 + n*16 + cl;
        int h = colo >> 6, dk = colo & 63;
        int row0 = M0 + wr*64 + m*16 + gp*4;       // 4 consecutive s
        int b = row0 >> 11, sp0 = row0 & (S_LEN - 1);
        ushort4 o4 = { f2bf(acc[m][n][0]), f2bf(acc[m][n][1]),
                       f2bf(acc[m][n][2]), f2bf(acc[m][n][3]) };
        *reinterpret_cast<ushort4*>(
            Vt + ((size_t)(b * NH + h) * DKH + dk) * S_LEN + sp0) = o4;
      }
    }
  }
}

// ---------- flash attention, causal, 32x32 swapped-QK in-register softmax ----
// grid (8, 64): block x handles q-blocks {x, 15-x} of 128 rows for bh = y.
// 4 waves x 32 q-rows. KV tile 64, double-buffered swizzled LDS, 2-deep
// reg-staged prefetch surviving lgkm-only barriers. S^T = mfma32(K,Q) puts
// each q-row's scores on one lane pair: softmax is in-lane + one
// shfl_xor(32) fold; the PV A-fragment is built in-register with
// compiler bf16 packing + shfl_xor(32) half-exchange (no LDS P staging).
__global__ __launch_bounds__(256)
void k_attn(const u16* __restrict__ Q, const u16* __restrict__ K,
            const u16* __restrict__ Vt, u16* __restrict__ Ob) {
  __shared__ u16 Ks[2][64 * 64];
  __shared__ u16 Vs[2][64 * 64];
  __shared__ float lbc[4][32];

  const int tid = threadIdx.x, lane = tid & 63, w = tid >> 6;
  const int rl = lane & 31, hf = lane >> 5;
  const int bh = blockIdx.y;
  const int pair = blockIdx.x;               // 0..7
  const u16* Qb = Q  + (size_t)bh * S_LEN * DKH;
  const u16* Kb = K  + (size_t)bh * S_LEN * DKH;
  const u16* Vb = Vt + (size_t)bh * DKH * S_LEN;
  const int b = bh >> 4, hd = bh & 15;

  // staging geometry: 2 x 16B per thread per matrix (coalesced global)
  const int srow = tid >> 3;                 // 0..31
  const int scol = (tid & 7) * 8;            // 0..56
  const int so0 = SWZ(srow, scol);
  const int so1 = SWZ(srow + 32, scol);
  const u16* kg0 = Kb + (size_t)srow * DKH + scol;
  const u16* kg1 = Kb + (size_t)(srow + 32) * DKH + scol;
  const u16* vg0 = Vb + (size_t)srow * S_LEN + scol;
  const u16* vg1 = Vb + (size_t)(srow + 32) * S_LEN + scol;

#pragma unroll 1
  for (int seg = 0; seg < 2; ++seg) {
    const int qb   = seg ? (15 - pair) : pair;
    const int T    = 2 * qb + 2;             // KV tiles (even, >= 2)
    const int qw32 = qb * 128 + w * 32;      // wave's q base
    const int diag = qw32 >> 6;              // wave's diagonal KV tile

    // Q fragments: lane rl = q-row, hf selects 8-wide k half of each 16-slice
    bf16x8 qf[4];
    {
      const u16* qp = Qb + (size_t)(qw32 + rl) * DKH + hf * 8;
#pragma unroll
      for (int s = 0; s < 4; ++s)
        qf[s] = *reinterpret_cast<const bf16x8*>(qp + s * 16);
    }

    f32x16 o0, o1;
#pragma unroll
    for (int r = 0; r < 16; ++r) { o0[r] = 0.f; o1[r] = 0.f; }
    float m = -1e30f, plr = 0.f;

    // prologue: tile 0 load -> LDS; prefetch tile 1
    uint4 kr0 = *reinterpret_cast<const uint4*>(kg0);
    uint4 kr1 = *reinterpret_cast<const uint4*>(kg1);
    uint4 vr0 = *reinterpret_cast<const uint4*>(vg0);
    uint4 vr1 = *reinterpret_cast<const uint4*>(vg1);
    wg_barrier();   // previous segment's LDS reads all complete
    *reinterpret_cast<uint4*>(&Ks[0][so0]) = kr0;
    *reinterpret_cast<uint4*>(&Ks[0][so1]) = kr1;
    *reinterpret_cast<uint4*>(&Vs[0][so0]) = vr0;
    *reinterpret_cast<uint4*>(&Vs[0][so1]) = vr1;
    kr0 = *reinterpret_cast<const uint4*>(kg0 + 64 * DKH);
    kr1 = *reinterpret_cast<const uint4*>(kg1 + 64 * DKH);
    vr0 = *reinterpret_cast<const uint4*>(vg0 + 64);
    vr1 = *reinterpret_cast<const uint4*>(vg1 + 64);

    int cur = 0;
#pragma unroll 1
    for (int t = 0; t < T; ++t) {
      wg_barrier();   // buf[cur] (tile t) visible; vmcnt prefetch survives
      const bool act = (t <= diag);
      float p[2][16];

      if (act) {
        f32x16 s0, s1;
#pragma unroll
        for (int r = 0; r < 16; ++r) { s0[r] = 0.f; s1[r] = 0.f; }
        __builtin_amdgcn_s_setprio(1);
#pragma unroll
        for (int s = 0; s < 4; ++s) {
          bf16x8 k0 = *reinterpret_cast<const bf16x8*>(
              &Ks[cur][SWZ(rl,      s * 16 + hf * 8)]);
          bf16x8 k1 = *reinterpret_cast<const bf16x8*>(
              &Ks[cur][SWZ(32 + rl, s * 16 + hf * 8)]);
          s0 = mfma32(k0, qf[s], s0);
          s1 = mfma32(k1, qf[s], s1);
        }
        __builtin_amdgcn_s_setprio(0);

        // causal mask, diagonal tile only
        if (t == diag) {
          const int qrel = qw32 + rl - t * 64;
#pragma unroll
          for (int r = 0; r < 16; ++r) {
            const int kl = KVLOC(r, hf);
            if (kl > qrel)      s0[r] = -1e30f;
            if (32 + kl > qrel) s1[r] = -1e30f;
          }
        }

        // row max: in-lane tree + half-fold (q-row rl lives on lanes rl, rl+32)
        float v[16];
#pragma unroll
        for (int r = 0; r < 16; ++r) v[r] = fmaxf(s0[r], s1[r]);
#pragma unroll
        for (int st = 8; st >= 1; st >>= 1)
#pragma unroll
          for (int r = 0; r < 8; ++r)
            if (r < st) v[r] = fmaxf(v[r], v[r + st]);
        const float mx = fmaxf(v[0], __shfl_xor(v[0], 32));

        if (__any(mx > m + DEFER_THR)) {     // rescale (first tile; then rare)
          const float mn = fmaxf(m, mx);
          const float al = fexp2((m - mn) * C_SC);
          m = mn;
          plr *= al;
          lbc[w][rl] = al;                   // lane-space -> reg-space bridge
          asm volatile("s_waitcnt lgkmcnt(0)" ::: "memory");
#pragma unroll
          for (int r = 0; r < 16; ++r) {
            const float alr = lbc[w][KVLOC(r, hf)];
            o0[r] *= alr; o1[r] *= alr;
          }
        }

        const float mC = m * C_SC;
#pragma unroll
        for (int r = 0; r < 16; ++r) {
          p[0][r] = fexp2(fmaf(s0[r], C_SC, -mC));
          p[1][r] = fexp2(fmaf(s1[r], C_SC, -mC));
        }
        float sv[16];
#pragma unroll
        for (int r = 0; r < 16; ++r) sv[r] = p[0][r] + p[1][r];
#pragma unroll
        for (int st = 8; st >= 1; st >>= 1)
#pragma unroll
          for (int r = 0; r < 8; ++r)
            if (r < st) sv[r] += sv[r + st];
        plr += sv[0];
      }

      // stage tile t+1 into other buffer; prefetch tile t+2
      if (t + 1 < T) {
        *reinterpret_cast<uint4*>(&Ks[cur ^ 1][so0]) = kr0;
        *reinterpret_cast<uint4*>(&Ks[cur ^ 1][so1]) = kr1;
        *reinterpret_cast<uint4*>(&Vs[cur ^ 1][so0]) = vr0;
        *reinterpret_cast<uint4*>(&Vs[cur ^ 1][so1]) = vr1;
        if (t + 2 < T) {
          const size_t ko = (size_t)(t + 2) * 64 * DKH;
          const size_t vo = (size_t)(t + 2) * 64;
          kr0 = *reinterpret_cast<const uint4*>(kg0 + ko);
          kr1 = *reinterpret_cast<const uint4*>(kg1 + ko);
          vr0 = *reinterpret_cast<const uint4*>(vg0 + vo);
          vr1 = *reinterpret_cast<const uint4*>(vg1 + vo);
        }
      }

      // O += P V : A-fragment built in-register. Lane (rl,hf) natively holds
      // p kv-offsets {4hf+0..3, 8+4hf+0..3, 16+..., 24+...}; the mfma A
      // layout needs contiguous kv 8hf..8hf+7 per 16-slice — exchange word
      // pairs with the partner half via shfl_xor(32) and select by hf.
      if (act) {
#pragma unroll
        for (int s = 0; s < 4; ++s) {
          const int n  = s >> 1;
          const int r0 = (s & 1) * 8;
          u32 aw = pk2(p[n][r0 + 0], p[n][r0 + 1]);
          u32 bw = pk2(p[n][r0 + 2], p[n][r0 + 3]);
          u32 cw = pk2(p[n][r0 + 4], p[n][r0 + 5]);
          u32 dw = pk2(p[n][r0 + 6], p[n][r0 + 7]);
          const u32 xa = (u32)__shfl_xor((int)aw, 32);
          const u32 xb = (u32)__shfl_xor((int)bw, 32);
          const u32 xc = (u32)__shfl_xor((int)cw, 32);
          const u32 xd = (u32)__shfl_xor((int)dw, 32);
          u32x4 fw = { hf ? xc : aw, hf ? xd : bw, hf ? cw : xa, hf ? dw : xb };
          bf16x8 af = __builtin_bit_cast(bf16x8, fw);
          bf16x8 v0 = *reinterpret_cast<const bf16x8*>(
              &Vs[cur][SWZ(rl,      s * 16 + hf * 8)]);
          bf16x8 v1 = *reinterpret_cast<const bf16x8*>(
              &Vs[cur][SWZ(32 + rl, s * 16 + hf * 8)]);
          __builtin_amdgcn_s_setprio(1);
          o0 = mfma32(af, v0, o0);
          o1 = mfma32(af, v1, o1);
          __builtin_amdgcn_s_setprio(0);
        }
      }
      cur ^= 1;
    }

    // epilogue: fold row sums, bridge 1/l to reg-space, store
    const float lsum = plr + __shfl_xor(plr, 32);
    lbc[w][rl] = 1.0f / lsum;
    asm volatile("s_waitcnt lgkmcnt(0)" ::: "memory");
#pragma unroll
    for (int r = 0; r < 16; ++r) {
      const float ivr = lbc[w][KVLOC(r, hf)];
      const int q = qw32 + KVLOC(r, hf);
      u16* op = Ob + ((size_t)(b * S_LEN + q)) * D_DIM + hd * DKH;
      op[rl]      = f2bf(o0[r] * ivr);
      op[32 + rl] = f2bf(o1[r] * ivr);
    }
  }
}

// ---------- output projection: out = attn * Wo^T, f32 stores ----------
__global__ __launch_bounds__(256)
void k_gemm_out(const u16* __restrict__ Ab, const u16* __restrict__ Wob,
                float* __restrict__ out) {
  __shared__ u16 As[128 * 64];
  __shared__ u16 Bs[128 * 64];
  int M0 = blockIdx.x * 128, N0 = blockIdx.y * 128;
  f32x4 zero = {0.f, 0.f, 0.f, 0.f};
  f32x4 acc[4][4];
#pragma unroll
  for (int m = 0; m < 4; ++m)
#pragma unroll
    for (int n = 0; n < 4; ++n) acc[m][n] = zero;

  gemm_tile(Ab, Wob, M0, N0, As, Bs, acc);

  int tid = threadIdx.x, lane = tid & 63, wave = tid >> 6;
  int cl = lane & 15, gp = lane >> 4;
  int wr = wave >> 1, wc = wave & 1;
#pragma unroll
  for (int m = 0; m < 4; ++m)
#pragma unroll
    for (int n = 0; n < 4; ++n)
#pragma unroll
      for (int r = 0; r < 4; ++r) {
        int row = M0 + wr*64 + m*16 + gp*4 + r;
        int col = N0 + wc*64 + n*16 + cl;
        out[(size_t)row * D_DIM + col] = acc[m][n][r];
      }
}

extern "C" void kernel_launch(void* const* d_in, const int* in_sizes, int n_in,
                              void* d_out, int out_size, void* d_ws, size_t ws_size,
                              hipStream_t stream) {
  const float* x  = (const float*)d_in[0];
  const float* Wq = (const float*)d_in[1];
  const float* Wk = (const float*)d_in[2];
  const float* Wv = (const float*)d_in[3];
  const float* Wo = (const float*)d_in[4];
  float* out = (float*)d_out;

  char* ws = (char*)d_ws;
  size_t off = 0;
  u16* xb  = (u16*)(ws + off); off += (size_t)M_ROWS * D_DIM * 2;   // 16 MB
  u16* wqb = (u16*)(ws + off); off += (size_t)D_DIM * D_DIM * 2;    // 2 MB
  u16* wkb = (u16*)(ws + off); off += (size_t)D_DIM * D_DIM * 2;
  u16* wvb = (u16*)(ws + off); off += (size_t)D_DIM * D_DIM * 2;
  u16* wob = (u16*)(ws + off); off += (size_t)D_DIM * D_DIM * 2;
  float2* tab = (float2*)(ws + off); off += (size_t)S_LEN * 32 * 8; // 0.5 MB
  u16* Qr = (u16*)(ws + off); off += (size_t)M_ROWS * D_DIM * 2;    // 16 MB
  u16* Kr = (u16*)(ws + off); off += (size_t)M_ROWS * D_DIM * 2;
  u16* Vt = (u16*)(ws + off); off += (size_t)M_ROWS * D_DIM * 2;
  u16* Ab = (u16*)(ws + off); off += (size_t)M_ROWS * D_DIM * 2;
  (void)ws_size; (void)in_sizes; (void)n_in; (void)out_size;

  k_cvt<<<8192, 256, 0, stream>>>(x,  xb,  (M_ROWS * D_DIM) / 4);
  k_cvt<<<1024, 256, 0, stream>>>(Wq, wqb, (D_DIM * D_DIM) / 4);
  k_cvt<<<1024, 256, 0, stream>>>(Wk, wkb, (D_DIM * D_DIM) / 4);
  k_cvt<<<1024, 256, 0, stream>>>(Wv, wvb, (D_DIM * D_DIM) / 4);
  k_cvt<<<1024, 256, 0, stream>>>(Wo, wob, (D_DIM * D_DIM) / 4);
  k_table<<<256, 256, 0, stream>>>(tab);

  k_gemm_qkv<<<dim3(64, 24), 256, 0, stream>>>(xb, wqb, wkb, wvb, tab, Qr, Kr, Vt);
  k_attn<<<dim3(8, 64), 256, 0, stream>>>(Qr, Kr, Vt, Ab);
  k_gemm_out<<<dim3(64, 8), 256, 0, stream>>>(Ab, wob, out);
}

// Round 6
// 241.060 us; speedup vs baseline: 1.5061x; 1.0190x over previous
//
#include <hip/hip_runtime.h>
#include <stdint.h>

typedef unsigned short u16;
typedef unsigned int   u32;
typedef __bf16  bf16x8 __attribute__((ext_vector_type(8)));
typedef float   f32x4  __attribute__((ext_vector_type(4)));
typedef float   f32x16 __attribute__((ext_vector_type(16)));
typedef unsigned int u32x4 __attribute__((ext_vector_type(4)));

#define B_SZ   4
#define S_LEN  2048
#define D_DIM  1024
#define NH     16
#define DKH    64
#define M_ROWS (B_SZ * S_LEN)   // 8192

// softmax scale folded into exp2 domain: 1/sqrt(64) * log2(e)
#define C_SC 0.1803368801111204f
// defer-max threshold in raw-score units: 8 / C_SC  (P bounded by 2^8)
#define DEFER_THR 44.36f

// kv/q row owned by (reg r, lane-half hf) in a 32x32 MFMA C/D fragment
#define KVLOC(r, hf) ((((r) & 3)) + 8 * ((r) >> 2) + 4 * (hf))

static __device__ __forceinline__ u16 f2bf(float f) {
  return __builtin_bit_cast(u16, (__bf16)f);
}

// pack two f32 -> dword of 2 bf16, element0 in low bits (compiler-generated)
static __device__ __forceinline__ u32 pk2(float lo, float hi) {
  ushort2 u = { f2bf(lo), f2bf(hi) };
  return __builtin_bit_cast(u32, u);
}

static __device__ __forceinline__ float fexp2(float x) {
  return __builtin_amdgcn_exp2f(x);
}

static __device__ __forceinline__ f32x4 mfma16(bf16x8 a, bf16x8 b, f32x4 c) {
  return __builtin_amdgcn_mfma_f32_16x16x32_bf16(a, b, c, 0, 0, 0);
}

static __device__ __forceinline__ f32x16 mfma32(bf16x8 a, bf16x8 b, f32x16 c) {
  return __builtin_amdgcn_mfma_f32_32x32x16_bf16(a, b, c, 0, 0, 0);
}

static __device__ __forceinline__ void gld_lds16(const u16* g, u16* l) {
  __builtin_amdgcn_global_load_lds(
      (const __attribute__((address_space(1))) u32*)g,
      (__attribute__((address_space(3))) u32*)l, 16, 0, 0);
}

// workgroup barrier that drains LDS ops only — outstanding global loads
// (vmcnt) survive across it when desired.
static __device__ __forceinline__ void wg_barrier() {
  asm volatile("s_waitcnt lgkmcnt(0)" ::: "memory");
  __builtin_amdgcn_s_barrier();
  __builtin_amdgcn_sched_barrier(0);
}

// XOR swizzle for row-major [R][64] u16 LDS tiles (read side). Write side is
// linear (global_load_lds) with the inverse permutation applied to the
// GLOBAL source address (same involution).
#define SWZ(row, col) (((row) * 64) + (((col) ^ (((row) & 7) << 3))))

// ---------- f32 -> bf16 conversion, 4 elems/thread ----------
__global__ void k_cvt(const float* __restrict__ src, u16* __restrict__ dst, int n4) {
  int i = blockIdx.x * blockDim.x + threadIdx.x;
  if (i >= n4) return;
  float4 v = reinterpret_cast<const float4*>(src)[i];
  ushort4 o = { f2bf(v.x), f2bf(v.y), f2bf(v.z), f2bf(v.w) };
  reinterpret_cast<ushort4*>(dst)[i] = o;
}

// ---------- RoPE table: tab[s*32+k] = (cos, sin) of s * 10000^(-k/32) ----------
__global__ void k_table(float2* __restrict__ tab) {
  int i = blockIdx.x * blockDim.x + threadIdx.x;   // 65536 total
  int s = i >> 5, k = i & 31;
  float freq = powf(10000.0f, -(float)k / 32.0f);
  float a = (float)s * freq;
  tab[i] = make_float2(cosf(a), sinf(a));
}

// ---------- shared 128x128xK GEMM core: C = A(M0 tile) * W^T(N0 tile) ----------
static __device__ __forceinline__ void gemm_tile(
    const u16* __restrict__ A, const u16* __restrict__ W,
    int M0, int N0, u16* As, u16* Bs, f32x4 acc[4][4]) {
  int tid = threadIdx.x;
  int lane = tid & 63, wave = tid >> 6;
  int cl = lane & 15, gp = lane >> 4;
  int wr = wave >> 1, wc = wave & 1;
  for (int t = 0; t < 16; ++t) {
    int k0 = t * 64;
#pragma unroll
    for (int i = 0; i < 4; ++i) {
      int chunk = i * 4 + wave;              // 0..15, wave-uniform
      int rowA  = chunk * 8 + (lane >> 3);   // 0..127
      int col   = (lane & 7) * 8;            // 0..56
      gld_lds16(A + (size_t)(M0 + rowA) * D_DIM + k0 + col, As + chunk * 512);
      gld_lds16(W + (size_t)(N0 + rowA) * D_DIM + k0 + col, Bs + chunk * 512);
    }
    __syncthreads();
#pragma unroll
    for (int kk = 0; kk < 2; ++kk) {
      bf16x8 af[4], bfr[4];
#pragma unroll
      for (int m = 0; m < 4; ++m)
        af[m] = *reinterpret_cast<const bf16x8*>(As + (wr*64 + m*16 + cl)*64 + kk*32 + gp*8);
#pragma unroll
      for (int n = 0; n < 4; ++n)
        bfr[n] = *reinterpret_cast<const bf16x8*>(Bs + (wc*64 + n*16 + cl)*64 + kk*32 + gp*8);
#pragma unroll
      for (int m = 0; m < 4; ++m)
#pragma unroll
        for (int n = 0; n < 4; ++n)
          acc[m][n] = mfma16(af[m], bfr[n], acc[m][n]);
    }
    __syncthreads();
  }
}

// ---------- QKV projection + RoPE + layout ----------
__global__ __launch_bounds__(256)
void k_gemm_qkv(const u16* __restrict__ Xb,
                const u16* __restrict__ Wqb, const u16* __restrict__ Wkb,
                const u16* __restrict__ Wvb,
                const float2* __restrict__ tab,
                u16* __restrict__ Qr, u16* __restrict__ Kr, u16* __restrict__ Vt) {
  __shared__ u16 As[128 * 64];
  __shared__ u16 Bs[128 * 64];
  int by   = blockIdx.y;
  int proj = by >> 3;
  int N0   = (by & 7) * 128;
  int M0   = blockIdx.x * 128;
  const u16* W = (proj == 0) ? Wqb : ((proj == 1) ? Wkb : Wvb);

  f32x4 zero = {0.f, 0.f, 0.f, 0.f};
  f32x4 acc[4][4];
#pragma unroll
  for (int m = 0; m < 4; ++m)
#pragma unroll
    for (int n = 0; n < 4; ++n) acc[m][n] = zero;

  gemm_tile(Xb, W, M0, N0, As, Bs, acc);

  int tid = threadIdx.x, lane = tid & 63, wave = tid >> 6;
  int cl = lane & 15, gp = lane >> 4;
  int wr = wave >> 1, wc = wave & 1;

  if (proj < 2) {
    u16* dst = (proj == 0) ? Qr : Kr;
#pragma unroll
    for (int m = 0; m < 4; ++m) {
#pragma unroll
      for (int n = 0; n < 4; ++n) {
        int colo = N0 + wc*64 + n*16 + cl;        // 0..1023
        int h = colo >> 6, dk = colo & 63;
        int kf = dk >> 1, par = dk & 1;
#pragma unroll
        for (int r = 0; r < 4; ++r) {
          int row = M0 + wr*64 + m*16 + gp*4 + r;  // global (b*S+s)
          int b = row >> 11, sp = row & (S_LEN - 1);
          float v = acc[m][n][r];
          float p = __shfl_xor(v, 1);              // partner column (2k<->2k+1)
          float2 cs = tab[sp * 32 + kf];
          float o = par ? (v * cs.x + p * cs.y) : (v * cs.x - p * cs.y);
          dst[((size_t)(b * NH + h) * S_LEN + sp) * DKH + dk] = f2bf(o);
        }
      }
    }
  } else {
#pragma unroll
    for (int m = 0; m < 4; ++m) {
#pragma unroll
      for (int n = 0; n < 4; ++n) {
        int colo = N0 + wc*64 + n*16 + cl;
        int h = colo >> 6, dk = colo & 63;
        int row0 = M0 + wr*64 + m*16 + gp*4;       // 4 consecutive s
        int b = row0 >> 11, sp0 = row0 & (S_LEN - 1);
        ushort4 o4 = { f2bf(acc[m][n][0]), f2bf(acc[m][n][1]),
                       f2bf(acc[m][n][2]), f2bf(acc[m][n][3]) };
        *reinterpret_cast<ushort4*>(
            Vt + ((size_t)(b * NH + h) * DKH + dk) * S_LEN + sp0) = o4;
      }
    }
  }
}

// ---------- flash attention, causal, 32x32 swapped-QK in-register softmax ----
// grid (16, 64): block x -> q-block (15 - x) of 128 rows for bh = y (big
// blocks dispatch first). 4 waves x 32 q-rows. KV tile 64, double-buffered
// LDS staged by global_load_lds DMA with source-side swizzle; 1-tile-ahead
// prefetch with vmcnt drained only after the compute phase.
__global__ __launch_bounds__(256, 4)
void k_attn(const u16* __restrict__ Q, const u16* __restrict__ K,
            const u16* __restrict__ Vt, u16* __restrict__ Ob) {
  __shared__ u16 Ks[2][64 * 64];
  __shared__ u16 Vs[2][64 * 64];
  __shared__ float lbc[4][32];

  const int tid = threadIdx.x, lane = tid & 63, w = tid >> 6;
  const int rl = lane & 31, hf = lane >> 5;
  const int bh = blockIdx.y;
  const int qb = 15 - blockIdx.x;            // 0..15, big first
  const u16* Qb = Q  + (size_t)bh * S_LEN * DKH;
  const u16* Kb = K  + (size_t)bh * S_LEN * DKH;
  const u16* Vb = Vt + (size_t)bh * DKH * S_LEN;
  const int b = bh >> 4, hd = bh & 15;

  // DMA staging: wave w, issue i covers rows i*32 + w*8 .. +7 (1 KB).
  // LDS dest is linear (base + lane*16B); the swizzle permutes the GLOBAL
  // source column-group instead: lane l reads col-group (l&7)^(l>>3) of
  // row (l>>3) — the same involution the SWZ read applies.
  const int lr = lane >> 3;                  // 0..7
  const int lg = (lane & 7) ^ lr;            // swizzled col group
  const u16* kb_l = Kb + (w * 8 + lr) * DKH + lg * 8;
  const u16* vb_l = Vb + (size_t)(w * 8 + lr) * S_LEN + lg * 8;

#define STAGE(buf_, t_) do {                                                 \
    gld_lds16(kb_l + (size_t)(t_) * 64 * DKH,        &Ks[buf_][(w*8)*64]);   \
    gld_lds16(kb_l + (size_t)(t_) * 64 * DKH + 2048, &Ks[buf_][(32+w*8)*64]);\
    gld_lds16(vb_l + (t_) * 64,                      &Vs[buf_][(w*8)*64]);   \
    gld_lds16(vb_l + (t_) * 64 + 32 * S_LEN,         &Vs[buf_][(32+w*8)*64]);\
  } while (0)

  const int T    = 2 * qb + 2;               // KV tiles
  const int qw32 = qb * 128 + w * 32;        // wave's q base
  const int diag = qw32 >> 6;                // wave's diagonal KV tile

  // Q fragments: lane rl = q-row, hf selects 8-wide k half of each 16-slice
  bf16x8 qf[4];
  {
    const u16* qp = Qb + (size_t)(qw32 + rl) * DKH + hf * 8;
#pragma unroll
    for (int s = 0; s < 4; ++s)
      qf[s] = *reinterpret_cast<const bf16x8*>(qp + s * 16);
  }

  f32x16 o0, o1;
#pragma unroll
  for (int r = 0; r < 16; ++r) { o0[r] = 0.f; o1[r] = 0.f; }
  float m = -1e30f, plr = 0.f;

  // prologue: tile 0 DMA, drain, barrier
  STAGE(0, 0);
  asm volatile("s_waitcnt vmcnt(0)" ::: "memory");
  __builtin_amdgcn_s_barrier();

  int cur = 0;
#pragma unroll 1
  for (int t = 0; t < T; ++t) {
    // issue next tile's DMA into the other buffer (prev reads drained at
    // the barrier that opened this tile)
    if (t + 1 < T) STAGE(cur ^ 1, t + 1);

    const bool act = (t <= diag);
    float p[2][16];

    if (act) {
      f32x16 s0, s1;
#pragma unroll
      for (int r = 0; r < 16; ++r) { s0[r] = 0.f; s1[r] = 0.f; }
      __builtin_amdgcn_s_setprio(1);
#pragma unroll
      for (int s = 0; s < 4; ++s) {
        bf16x8 k0 = *reinterpret_cast<const bf16x8*>(
            &Ks[cur][SWZ(rl,      s * 16 + hf * 8)]);
        bf16x8 k1 = *reinterpret_cast<const bf16x8*>(
            &Ks[cur][SWZ(32 + rl, s * 16 + hf * 8)]);
        s0 = mfma32(k0, qf[s], s0);
        s1 = mfma32(k1, qf[s], s1);
      }
      __builtin_amdgcn_s_setprio(0);

      // causal mask, diagonal tile only
      if (t == diag) {
        const int qrel = qw32 + rl - t * 64;
#pragma unroll
        for (int r = 0; r < 16; ++r) {
          const int kl = KVLOC(r, hf);
          if (kl > qrel)      s0[r] = -1e30f;
          if (32 + kl > qrel) s1[r] = -1e30f;
        }
      }

      // row max: in-lane tree + half-fold (q-row rl lives on lanes rl, rl+32)
      float v[16];
#pragma unroll
      for (int r = 0; r < 16; ++r) v[r] = fmaxf(s0[r], s1[r]);
#pragma unroll
      for (int st = 8; st >= 1; st >>= 1)
#pragma unroll
        for (int r = 0; r < 8; ++r)
          if (r < st) v[r] = fmaxf(v[r], v[r + st]);
      const float mx = fmaxf(v[0], __shfl_xor(v[0], 32));

      if (__any(mx > m + DEFER_THR)) {       // rescale (first tile; then rare)
        const float mn = fmaxf(m, mx);
        const float al = fexp2((m - mn) * C_SC);
        m = mn;
        plr *= al;
        lbc[w][rl] = al;                     // lane-space -> reg-space bridge
        asm volatile("s_waitcnt lgkmcnt(0)" ::: "memory");
#pragma unroll
        for (int r = 0; r < 16; ++r) {
          const float alr = lbc[w][KVLOC(r, hf)];
          o0[r] *= alr; o1[r] *= alr;
        }
      }

      const float mC = m * C_SC;
#pragma unroll
      for (int r = 0; r < 16; ++r) {
        p[0][r] = fexp2(fmaf(s0[r], C_SC, -mC));
        p[1][r] = fexp2(fmaf(s1[r], C_SC, -mC));
      }
      float sv[16];
#pragma unroll
      for (int r = 0; r < 16; ++r) sv[r] = p[0][r] + p[1][r];
#pragma unroll
      for (int st = 8; st >= 1; st >>= 1)
#pragma unroll
        for (int r = 0; r < 8; ++r)
          if (r < st) sv[r] += sv[r + st];
      plr += sv[0];

      // O += P V : A-fragment built in-register. Lane (rl,hf) natively holds
      // p kv-offsets {4hf+0..3, 8+4hf+0..3, ...}; the mfma A layout needs
      // contiguous kv 8hf..8hf+7 per 16-slice — exchange word pairs with the
      // partner half via shfl_xor(32) and select by hf.
#pragma unroll
      for (int s = 0; s < 4; ++s) {
        const int n  = s >> 1;
        const int r0 = (s & 1) * 8;
        u32 aw = pk2(p[n][r0 + 0], p[n][r0 + 1]);
        u32 bw = pk2(p[n][r0 + 2], p[n][r0 + 3]);
        u32 cw = pk2(p[n][r0 + 4], p[n][r0 + 5]);
        u32 dw = pk2(p[n][r0 + 6], p[n][r0 + 7]);
        const u32 xa = (u32)__shfl_xor((int)aw, 32);
        const u32 xb = (u32)__shfl_xor((int)bw, 32);
        const u32 xc = (u32)__shfl_xor((int)cw, 32);
        const u32 xd = (u32)__shfl_xor((int)dw, 32);
        u32x4 fw = { hf ? xc : aw, hf ? xd : bw, hf ? cw : xa, hf ? dw : xb };
        bf16x8 af = __builtin_bit_cast(bf16x8, fw);
        bf16x8 v0 = *reinterpret_cast<const bf16x8*>(
            &Vs[cur][SWZ(rl,      s * 16 + hf * 8)]);
        bf16x8 v1 = *reinterpret_cast<const bf16x8*>(
            &Vs[cur][SWZ(32 + rl, s * 16 + hf * 8)]);
        __builtin_amdgcn_s_setprio(1);
        o0 = mfma32(af, v0, o0);
        o1 = mfma32(af, v1, o1);
        __builtin_amdgcn_s_setprio(0);
      }
    }

    // next tile's DMA must be complete before anyone reads it
    asm volatile("s_waitcnt vmcnt(0)" ::: "memory");
    wg_barrier();
    cur ^= 1;
  }

  // epilogue: fold row sums, bridge 1/l to reg-space, store
  const float lsum = plr + __shfl_xor(plr, 32);
  lbc[w][rl] = 1.0f / lsum;
  asm volatile("s_waitcnt lgkmcnt(0)" ::: "memory");
#pragma unroll
  for (int r = 0; r < 16; ++r) {
    const float ivr = lbc[w][KVLOC(r, hf)];
    const int q = qw32 + KVLOC(r, hf);
    u16* op = Ob + ((size_t)(b * S_LEN + q)) * D_DIM + hd * DKH;
    op[rl]      = f2bf(o0[r] * ivr);
    op[32 + rl] = f2bf(o1[r] * ivr);
  }
#undef STAGE
}

// ---------- output projection: out = attn * Wo^T, f32 stores ----------
__global__ __launch_bounds__(256)
void k_gemm_out(const u16* __restrict__ Ab, const u16* __restrict__ Wob,
                float* __restrict__ out) {
  __shared__ u16 As[128 * 64];
  __shared__ u16 Bs[128 * 64];
  int M0 = blockIdx.x * 128, N0 = blockIdx.y * 128;
  f32x4 zero = {0.f, 0.f, 0.f, 0.f};
  f32x4 acc[4][4];
#pragma unroll
  for (int m = 0; m < 4; ++m)
#pragma unroll
    for (int n = 0; n < 4; ++n) acc[m][n] = zero;

  gemm_tile(Ab, Wob, M0, N0, As, Bs, acc);

  int tid = threadIdx.x, lane = tid & 63, wave = tid >> 6;
  int cl = lane & 15, gp = lane >> 4;
  int wr = wave >> 1, wc = wave & 1;
#pragma unroll
  for (int m = 0; m < 4; ++m)
#pragma unroll
    for (int n = 0; n < 4; ++n)
#pragma unroll
      for (int r = 0; r < 4; ++r) {
        int row = M0 + wr*64 + m*16 + gp*4 + r;
        int col = N0 + wc*64 + n*16 + cl;
        out[(size_t)row * D_DIM + col] = acc[m][n][r];
      }
}

extern "C" void kernel_launch(void* const* d_in, const int* in_sizes, int n_in,
                              void* d_out, int out_size, void* d_ws, size_t ws_size,
                              hipStream_t stream) {
  const float* x  = (const float*)d_in[0];
  const float* Wq = (const float*)d_in[1];
  const float* Wk = (const float*)d_in[2];
  const float* Wv = (const float*)d_in[3];
  const float* Wo = (const float*)d_in[4];
  float* out = (float*)d_out;

  char* ws = (char*)d_ws;
  size_t off = 0;
  u16* xb  = (u16*)(ws + off); off += (size_t)M_ROWS * D_DIM * 2;   // 16 MB
  u16* wqb = (u16*)(ws + off); off += (size_t)D_DIM * D_DIM * 2;    // 2 MB
  u16* wkb = (u16*)(ws + off); off += (size_t)D_DIM * D_DIM * 2;
  u16* wvb = (u16*)(ws + off); off += (size_t)D_DIM * D_DIM * 2;
  u16* wob = (u16*)(ws + off); off += (size_t)D_DIM * D_DIM * 2;
  float2* tab = (float2*)(ws + off); off += (size_t)S_LEN * 32 * 8; // 0.5 MB
  u16* Qr = (u16*)(ws + off); off += (size_t)M_ROWS * D_DIM * 2;    // 16 MB
  u16* Kr = (u16*)(ws + off); off += (size_t)M_ROWS * D_DIM * 2;
  u16* Vt = (u16*)(ws + off); off += (size_t)M_ROWS * D_DIM * 2;
  u16* Ab = (u16*)(ws + off); off += (size_t)M_ROWS * D_DIM * 2;
  (void)ws_size; (void)in_sizes; (void)n_in; (void)out_size;

  k_cvt<<<8192, 256, 0, stream>>>(x,  xb,  (M_ROWS * D_DIM) / 4);
  k_cvt<<<1024, 256, 0, stream>>>(Wq, wqb, (D_DIM * D_DIM) / 4);
  k_cvt<<<1024, 256, 0, stream>>>(Wk, wkb, (D_DIM * D_DIM) / 4);
  k_cvt<<<1024, 256, 0, stream>>>(Wv, wvb, (D_DIM * D_DIM) / 4);
  k_cvt<<<1024, 256, 0, stream>>>(Wo, wob, (D_DIM * D_DIM) / 4);
  k_table<<<256, 256, 0, stream>>>(tab);

  k_gemm_qkv<<<dim3(64, 24), 256, 0, stream>>>(xb, wqb, wkb, wvb, tab, Qr, Kr, Vt);
  k_attn<<<dim3(16, 64), 256, 0, stream>>>(Qr, Kr, Vt, Ab);
  k_gemm_out<<<dim3(64, 8), 256, 0, stream>>>(Ab, wob, out);
}

// Round 7
// 235.892 us; speedup vs baseline: 1.5391x; 1.0219x over previous
//
#include <hip/hip_runtime.h>
#include <stdint.h>

typedef unsigned short u16;
typedef unsigned int   u32;
typedef __bf16  bf16x8 __attribute__((ext_vector_type(8)));
typedef float   f32x4  __attribute__((ext_vector_type(4)));
typedef float   f32x16 __attribute__((ext_vector_type(16)));
typedef unsigned int u32x4 __attribute__((ext_vector_type(4)));

#define B_SZ   4
#define S_LEN  2048
#define D_DIM  1024
#define NH     16
#define DKH    64
#define M_ROWS (B_SZ * S_LEN)   // 8192

// softmax scale folded into exp2 domain: 1/sqrt(64) * log2(e)
#define C_SC 0.1803368801111204f
// defer-max threshold in raw-score units: 8 / C_SC  (P bounded by 2^8)
#define DEFER_THR 44.36f

// kv/q row owned by (reg r, lane-half hf) in a 32x32 MFMA C/D fragment
#define KVLOC(r, hf) ((((r) & 3)) + 8 * ((r) >> 2) + 4 * (hf))

static __device__ __forceinline__ u16 f2bf(float f) {
  return __builtin_bit_cast(u16, (__bf16)f);
}

// pack two f32 -> dword of 2 bf16, element0 in low bits (compiler-generated)
static __device__ __forceinline__ u32 pk2(float lo, float hi) {
  ushort2 u = { f2bf(lo), f2bf(hi) };
  return __builtin_bit_cast(u32, u);
}

static __device__ __forceinline__ float fexp2(float x) {
  return __builtin_amdgcn_exp2f(x);
}

static __device__ __forceinline__ f32x4 mfma16(bf16x8 a, bf16x8 b, f32x4 c) {
  return __builtin_amdgcn_mfma_f32_16x16x32_bf16(a, b, c, 0, 0, 0);
}

static __device__ __forceinline__ f32x16 mfma32(bf16x8 a, bf16x8 b, f32x16 c) {
  return __builtin_amdgcn_mfma_f32_32x32x16_bf16(a, b, c, 0, 0, 0);
}

static __device__ __forceinline__ void gld_lds16(const u16* g, u16* l) {
  __builtin_amdgcn_global_load_lds(
      (const __attribute__((address_space(1))) u32*)g,
      (__attribute__((address_space(3))) u32*)l, 16, 0, 0);
}

// workgroup barrier that drains LDS ops only — outstanding global loads
// (vmcnt) survive across it when desired.
static __device__ __forceinline__ void wg_barrier() {
  asm volatile("s_waitcnt lgkmcnt(0)" ::: "memory");
  __builtin_amdgcn_s_barrier();
  __builtin_amdgcn_sched_barrier(0);
}

// XOR swizzle for row-major [R][64] u16 LDS tiles (read side). Write side is
// linear (global_load_lds) with the inverse permutation applied to the
// GLOBAL source address (same involution).
#define SWZ(row, col) (((row) * 64) + (((col) ^ (((row) & 7) << 3))))

// ---------- f32 -> bf16 conversion, 4 elems/thread ----------
__global__ void k_cvt(const float* __restrict__ src, u16* __restrict__ dst, int n4) {
  int i = blockIdx.x * blockDim.x + threadIdx.x;
  if (i >= n4) return;
  float4 v = reinterpret_cast<const float4*>(src)[i];
  ushort4 o = { f2bf(v.x), f2bf(v.y), f2bf(v.z), f2bf(v.w) };
  reinterpret_cast<ushort4*>(dst)[i] = o;
}

// ---------- RoPE table: tab[s*32+k] = (cos, sin) of s * 10000^(-k/32) ----------
__global__ void k_table(float2* __restrict__ tab) {
  int i = blockIdx.x * blockDim.x + threadIdx.x;   // 65536 total
  int s = i >> 5, k = i & 31;
  float freq = powf(10000.0f, -(float)k / 32.0f);
  float a = (float)s * freq;
  tab[i] = make_float2(cosf(a), sinf(a));
}

// ---------- shared 128x128xK GEMM core: C = A(M0 tile) * W^T(N0 tile) ----------
static __device__ __forceinline__ void gemm_tile(
    const u16* __restrict__ A, const u16* __restrict__ W,
    int M0, int N0, u16* As, u16* Bs, f32x4 acc[4][4]) {
  int tid = threadIdx.x;
  int lane = tid & 63, wave = tid >> 6;
  int cl = lane & 15, gp = lane >> 4;
  int wr = wave >> 1, wc = wave & 1;
  for (int t = 0; t < 16; ++t) {
    int k0 = t * 64;
#pragma unroll
    for (int i = 0; i < 4; ++i) {
      int chunk = i * 4 + wave;              // 0..15, wave-uniform
      int rowA  = chunk * 8 + (lane >> 3);   // 0..127
      int col   = (lane & 7) * 8;            // 0..56
      gld_lds16(A + (size_t)(M0 + rowA) * D_DIM + k0 + col, As + chunk * 512);
      gld_lds16(W + (size_t)(N0 + rowA) * D_DIM + k0 + col, Bs + chunk * 512);
    }
    __syncthreads();
#pragma unroll
    for (int kk = 0; kk < 2; ++kk) {
      bf16x8 af[4], bfr[4];
#pragma unroll
      for (int m = 0; m < 4; ++m)
        af[m] = *reinterpret_cast<const bf16x8*>(As + (wr*64 + m*16 + cl)*64 + kk*32 + gp*8);
#pragma unroll
      for (int n = 0; n < 4; ++n)
        bfr[n] = *reinterpret_cast<const bf16x8*>(Bs + (wc*64 + n*16 + cl)*64 + kk*32 + gp*8);
#pragma unroll
      for (int m = 0; m < 4; ++m)
#pragma unroll
        for (int n = 0; n < 4; ++n)
          acc[m][n] = mfma16(af[m], bfr[n], acc[m][n]);
    }
    __syncthreads();
  }
}

// ---------- QKV projection + RoPE + layout ----------
__global__ __launch_bounds__(256)
void k_gemm_qkv(const u16* __restrict__ Xb,
                const u16* __restrict__ Wqb, const u16* __restrict__ Wkb,
                const u16* __restrict__ Wvb,
                const float2* __restrict__ tab,
                u16* __restrict__ Qr, u16* __restrict__ Kr, u16* __restrict__ Vt) {
  __shared__ u16 As[128 * 64];
  __shared__ u16 Bs[128 * 64];
  int by   = blockIdx.y;
  int proj = by >> 3;
  int N0   = (by & 7) * 128;
  int M0   = blockIdx.x * 128;
  const u16* W = (proj == 0) ? Wqb : ((proj == 1) ? Wkb : Wvb);

  f32x4 zero = {0.f, 0.f, 0.f, 0.f};
  f32x4 acc[4][4];
#pragma unroll
  for (int m = 0; m < 4; ++m)
#pragma unroll
    for (int n = 0; n < 4; ++n) acc[m][n] = zero;

  gemm_tile(Xb, W, M0, N0, As, Bs, acc);

  int tid = threadIdx.x, lane = tid & 63, wave = tid >> 6;
  int cl = lane & 15, gp = lane >> 4;
  int wr = wave >> 1, wc = wave & 1;

  if (proj < 2) {
    u16* dst = (proj == 0) ? Qr : Kr;
#pragma unroll
    for (int m = 0; m < 4; ++m) {
#pragma unroll
      for (int n = 0; n < 4; ++n) {
        int colo = N0 + wc*64 + n*16 + cl;        // 0..1023
        int h = colo >> 6, dk = colo & 63;
        int kf = dk >> 1, par = dk & 1;
#pragma unroll
        for (int r = 0; r < 4; ++r) {
          int row = M0 + wr*64 + m*16 + gp*4 + r;  // global (b*S+s)
          int b = row >> 11, sp = row & (S_LEN - 1);
          float v = acc[m][n][r];
          float p = __shfl_xor(v, 1);              // partner column (2k<->2k+1)
          float2 cs = tab[sp * 32 + kf];
          float o = par ? (v * cs.x + p * cs.y) : (v * cs.x - p * cs.y);
          dst[((size_t)(b * NH + h) * S_LEN + sp) * DKH + dk] = f2bf(o);
        }
      }
    }
  } else {
#pragma unroll
    for (int m = 0; m < 4; ++m) {
#pragma unroll
      for (int n = 0; n < 4; ++n) {
        int colo = N0 + wc*64 + n*16 + cl;
        int h = colo >> 6, dk = colo & 63;
        int row0 = M0 + wr*64 + m*16 + gp*4;       // 4 consecutive s
        int b = row0 >> 11, sp0 = row0 & (S_LEN - 1);
        ushort4 o4 = { f2bf(acc[m][n][0]), f2bf(acc[m][n][1]),
                       f2bf(acc[m][n][2]), f2bf(acc[m][n][3]) };
        *reinterpret_cast<ushort4*>(
            Vt + ((size_t)(b * NH + h) * DKH + dk) * S_LEN + sp0) = o4;
      }
    }
  }
}

// ---------- flash attention, causal, 32x32 swapped-QK in-register softmax ----
// grid 1024 (1-D, XCD-aware): xcd = id&7 owns bh group (id&7)*8 + (slot>>4);
// qb = 15 - (slot&15) (big blocks first). All 16 q-blocks of a bh live on one
// XCD -> its K/V stays L2-resident (8 bh x 512 KB = 4 MB/XCD).
// 4 waves x 32 q-rows. KV tile 64, double-buffered LDS via global_load_lds
// DMA with source-side swizzle; PV reads V kv-permuted so the P fragment
// needs NO cross-lane exchange (A/B only have to agree per k-slot).
__global__ __launch_bounds__(256, 4)
void k_attn(const u16* __restrict__ Q, const u16* __restrict__ K,
            const u16* __restrict__ Vt, u16* __restrict__ Ob) {
  __shared__ u16 Ks[2][64 * 64];
  __shared__ u16 Vs[2][64 * 64];
  __shared__ float lbc[4][32];

  const int tid = threadIdx.x, lane = tid & 63, w = tid >> 6;
  const int rl = lane & 31, hf = lane >> 5;
  const int id   = blockIdx.x;
  const int slot = id >> 3;                  // 0..127 within XCD
  const int bh   = ((id & 7) << 3) | (slot >> 4);
  const int qb   = 15 - (slot & 15);         // big first within bh group
  const u16* Qb = Q  + (size_t)bh * S_LEN * DKH;
  const u16* Kb = K  + (size_t)bh * S_LEN * DKH;
  const u16* Vb = Vt + (size_t)bh * DKH * S_LEN;
  const int b = bh >> 4, hd = bh & 15;

  // DMA staging: wave w, issue i covers rows i*32 + w*8 .. +7 (1 KB).
  // LDS dest is linear (base + lane*16B); the swizzle permutes the GLOBAL
  // source column-group instead: lane l reads col-group (l&7)^(l>>3) of
  // row (l>>3) — the same involution the SWZ read applies.
  const int lr = lane >> 3;                  // 0..7
  const int lg = (lane & 7) ^ lr;            // swizzled col group
  const u16* kb_l = Kb + (w * 8 + lr) * DKH + lg * 8;
  const u16* vb_l = Vb + (size_t)(w * 8 + lr) * S_LEN + lg * 8;

#define STAGE(buf_, t_) do {                                                 \
    gld_lds16(kb_l + (size_t)(t_) * 64 * DKH,        &Ks[buf_][(w*8)*64]);   \
    gld_lds16(kb_l + (size_t)(t_) * 64 * DKH + 2048, &Ks[buf_][(32+w*8)*64]);\
    gld_lds16(vb_l + (t_) * 64,                      &Vs[buf_][(w*8)*64]);   \
    gld_lds16(vb_l + (t_) * 64 + 32 * S_LEN,         &Vs[buf_][(32+w*8)*64]);\
  } while (0)

  const int T    = 2 * qb + 2;               // KV tiles
  const int qw32 = qb * 128 + w * 32;        // wave's q base
  const int diag = qw32 >> 6;                // wave's diagonal KV tile

  // Q fragments: lane rl = q-row, hf selects 8-wide k half of each 16-slice
  bf16x8 qf[4];
  {
    const u16* qp = Qb + (size_t)(qw32 + rl) * DKH + hf * 8;
#pragma unroll
    for (int s = 0; s < 4; ++s)
      qf[s] = *reinterpret_cast<const bf16x8*>(qp + s * 16);
  }

  f32x16 o0, o1;
#pragma unroll
  for (int r = 0; r < 16; ++r) { o0[r] = 0.f; o1[r] = 0.f; }
  float m = -1e30f, plr = 0.f;

  // prologue: tile 0 DMA, drain, barrier
  STAGE(0, 0);
  asm volatile("s_waitcnt vmcnt(0)" ::: "memory");
  __builtin_amdgcn_s_barrier();

  int cur = 0;
#pragma unroll 1
  for (int t = 0; t < T; ++t) {
    // issue next tile's DMA into the other buffer (prev reads drained at
    // the barrier that opened this tile)
    if (t + 1 < T) STAGE(cur ^ 1, t + 1);

    const bool act = (t <= diag);
    float p[2][16];

    if (act) {
      f32x16 s0, s1;
#pragma unroll
      for (int r = 0; r < 16; ++r) { s0[r] = 0.f; s1[r] = 0.f; }
      __builtin_amdgcn_s_setprio(1);
#pragma unroll
      for (int s = 0; s < 4; ++s) {
        bf16x8 k0 = *reinterpret_cast<const bf16x8*>(
            &Ks[cur][SWZ(rl,      s * 16 + hf * 8)]);
        bf16x8 k1 = *reinterpret_cast<const bf16x8*>(
            &Ks[cur][SWZ(32 + rl, s * 16 + hf * 8)]);
        s0 = mfma32(k0, qf[s], s0);
        s1 = mfma32(k1, qf[s], s1);
      }
      __builtin_amdgcn_s_setprio(0);

      // causal mask, diagonal tile only
      if (t == diag) {
        const int qrel = qw32 + rl - t * 64;
#pragma unroll
        for (int r = 0; r < 16; ++r) {
          const int kl = KVLOC(r, hf);
          if (kl > qrel)      s0[r] = -1e30f;
          if (32 + kl > qrel) s1[r] = -1e30f;
        }
      }

      // row max: in-lane tree + half-fold (q-row rl lives on lanes rl, rl+32)
      float v[16];
#pragma unroll
      for (int r = 0; r < 16; ++r) v[r] = fmaxf(s0[r], s1[r]);
#pragma unroll
      for (int st = 8; st >= 1; st >>= 1)
#pragma unroll
        for (int r = 0; r < 8; ++r)
          if (r < st) v[r] = fmaxf(v[r], v[r + st]);
      const float mx = fmaxf(v[0], __shfl_xor(v[0], 32));

      if (__any(mx > m + DEFER_THR)) {       // rescale (first tile; then rare)
        const float mn = fmaxf(m, mx);
        const float al = fexp2((m - mn) * C_SC);
        m = mn;
        plr *= al;
        lbc[w][rl] = al;                     // lane-space -> reg-space bridge
        asm volatile("s_waitcnt lgkmcnt(0)" ::: "memory");
#pragma unroll
        for (int r = 0; r < 16; ++r) {
          const float alr = lbc[w][KVLOC(r, hf)];
          o0[r] *= alr; o1[r] *= alr;
        }
      }

      const float mC = m * C_SC;
#pragma unroll
      for (int r = 0; r < 16; ++r) {
        p[0][r] = fexp2(fmaf(s0[r], C_SC, -mC));
        p[1][r] = fexp2(fmaf(s1[r], C_SC, -mC));
      }
      float sv[16];
#pragma unroll
      for (int r = 0; r < 16; ++r) sv[r] = p[0][r] + p[1][r];
#pragma unroll
      for (int st = 8; st >= 1; st >>= 1)
#pragma unroll
        for (int r = 0; r < 8; ++r)
          if (r < st) sv[r] += sv[r + st];
      plr += sv[0];

      // O += P V, zero cross-lane: A keeps P's NATIVE slot order
      // (slot e of half hf <-> kv = 4hf + (e&3) + 8*(e>>2)); B supplies V
      // with kv-columns read in the SAME permuted order (two b64 reads at
      // cols s16+4hf and s16+8+4hf). MFMA only needs A/B slot agreement.
#pragma unroll
      for (int s = 0; s < 4; ++s) {
        const int n  = s >> 1;
        const int r0 = (s & 1) * 8;
        u32x4 fw = { pk2(p[n][r0 + 0], p[n][r0 + 1]),
                     pk2(p[n][r0 + 2], p[n][r0 + 3]),
                     pk2(p[n][r0 + 4], p[n][r0 + 5]),
                     pk2(p[n][r0 + 6], p[n][r0 + 7]) };
        bf16x8 af = __builtin_bit_cast(bf16x8, fw);
        uint2 va = *reinterpret_cast<const uint2*>(
            &Vs[cur][SWZ(rl,      s * 16 + 4 * hf)]);
        uint2 vb = *reinterpret_cast<const uint2*>(
            &Vs[cur][SWZ(rl,      s * 16 + 8 + 4 * hf)]);
        uint2 vc = *reinterpret_cast<const uint2*>(
            &Vs[cur][SWZ(32 + rl, s * 16 + 4 * hf)]);
        uint2 vd = *reinterpret_cast<const uint2*>(
            &Vs[cur][SWZ(32 + rl, s * 16 + 8 + 4 * hf)]);
        u32x4 v0w = { va.x, va.y, vb.x, vb.y };
        u32x4 v1w = { vc.x, vc.y, vd.x, vd.y };
        bf16x8 v0 = __builtin_bit_cast(bf16x8, v0w);
        bf16x8 v1 = __builtin_bit_cast(bf16x8, v1w);
        __builtin_amdgcn_s_setprio(1);
        o0 = mfma32(af, v0, o0);
        o1 = mfma32(af, v1, o1);
        __builtin_amdgcn_s_setprio(0);
      }
    }

    // next tile's DMA must be complete before anyone reads it
    asm volatile("s_waitcnt vmcnt(0)" ::: "memory");
    wg_barrier();
    cur ^= 1;
  }

  // epilogue: fold row sums, bridge 1/l to reg-space, store
  const float lsum = plr + __shfl_xor(plr, 32);
  lbc[w][rl] = 1.0f / lsum;
  asm volatile("s_waitcnt lgkmcnt(0)" ::: "memory");
#pragma unroll
  for (int r = 0; r < 16; ++r) {
    const float ivr = lbc[w][KVLOC(r, hf)];
    const int q = qw32 + KVLOC(r, hf);
    u16* op = Ob + ((size_t)(b * S_LEN + q)) * D_DIM + hd * DKH;
    op[rl]      = f2bf(o0[r] * ivr);
    op[32 + rl] = f2bf(o1[r] * ivr);
  }
#undef STAGE
}

// ---------- output projection: out = attn * Wo^T, f32 stores ----------
__global__ __launch_bounds__(256)
void k_gemm_out(const u16* __restrict__ Ab, const u16* __restrict__ Wob,
                float* __restrict__ out) {
  __shared__ u16 As[128 * 64];
  __shared__ u16 Bs[128 * 64];
  int M0 = blockIdx.x * 128, N0 = blockIdx.y * 128;
  f32x4 zero = {0.f, 0.f, 0.f, 0.f};
  f32x4 acc[4][4];
#pragma unroll
  for (int m = 0; m < 4; ++m)
#pragma unroll
    for (int n = 0; n < 4; ++n) acc[m][n] = zero;

  gemm_tile(Ab, Wob, M0, N0, As, Bs, acc);

  int tid = threadIdx.x, lane = tid & 63, wave = tid >> 6;
  int cl = lane & 15, gp = lane >> 4;
  int wr = wave >> 1, wc = wave & 1;
#pragma unroll
  for (int m = 0; m < 4; ++m)
#pragma unroll
    for (int n = 0; n < 4; ++n)
#pragma unroll
      for (int r = 0; r < 4; ++r) {
        int row = M0 + wr*64 + m*16 + gp*4 + r;
        int col = N0 + wc*64 + n*16 + cl;
        out[(size_t)row * D_DIM + col] = acc[m][n][r];
      }
}

extern "C" void kernel_launch(void* const* d_in, const int* in_sizes, int n_in,
                              void* d_out, int out_size, void* d_ws, size_t ws_size,
                              hipStream_t stream) {
  const float* x  = (const float*)d_in[0];
  const float* Wq = (const float*)d_in[1];
  const float* Wk = (const float*)d_in[2];
  const float* Wv = (const float*)d_in[3];
  const float* Wo = (const float*)d_in[4];
  float* out = (float*)d_out;

  char* ws = (char*)d_ws;
  size_t off = 0;
  u16* xb  = (u16*)(ws + off); off += (size_t)M_ROWS * D_DIM * 2;   // 16 MB
  u16* wqb = (u16*)(ws + off); off += (size_t)D_DIM * D_DIM * 2;    // 2 MB
  u16* wkb = (u16*)(ws + off); off += (size_t)D_DIM * D_DIM * 2;
  u16* wvb = (u16*)(ws + off); off += (size_t)D_DIM * D_DIM * 2;
  u16* wob = (u16*)(ws + off); off += (size_t)D_DIM * D_DIM * 2;
  float2* tab = (float2*)(ws + off); off += (size_t)S_LEN * 32 * 8; // 0.5 MB
  u16* Qr = (u16*)(ws + off); off += (size_t)M_ROWS * D_DIM * 2;    // 16 MB
  u16* Kr = (u16*)(ws + off); off += (size_t)M_ROWS * D_DIM * 2;
  u16* Vt = (u16*)(ws + off); off += (size_t)M_ROWS * D_DIM * 2;
  u16* Ab = (u16*)(ws + off); off += (size_t)M_ROWS * D_DIM * 2;
  (void)ws_size; (void)in_sizes; (void)n_in; (void)out_size;

  k_cvt<<<8192, 256, 0, stream>>>(x,  xb,  (M_ROWS * D_DIM) / 4);
  k_cvt<<<1024, 256, 0, stream>>>(Wq, wqb, (D_DIM * D_DIM) / 4);
  k_cvt<<<1024, 256, 0, stream>>>(Wk, wkb, (D_DIM * D_DIM) / 4);
  k_cvt<<<1024, 256, 0, stream>>>(Wv, wvb, (D_DIM * D_DIM) / 4);
  k_cvt<<<1024, 256, 0, stream>>>(Wo, wob, (D_DIM * D_DIM) / 4);
  k_table<<<256, 256, 0, stream>>>(tab);

  k_gemm_qkv<<<dim3(64, 24), 256, 0, stream>>>(xb, wqb, wkb, wvb, tab, Qr, Kr, Vt);
  k_attn<<<dim3(1024), 256, 0, stream>>>(Qr, Kr, Vt, Ab);
  k_gemm_out<<<dim3(64, 8), 256, 0, stream>>>(Ab, wob, out);
}

// Round 8
// 229.998 us; speedup vs baseline: 1.5786x; 1.0256x over previous
//
#include <hip/hip_runtime.h>
#include <stdint.h>

typedef unsigned short u16;
typedef unsigned int   u32;
typedef __bf16  bf16x8 __attribute__((ext_vector_type(8)));
typedef float   f32x4  __attribute__((ext_vector_type(4)));
typedef float   f32x16 __attribute__((ext_vector_type(16)));
typedef unsigned int u32x4 __attribute__((ext_vector_type(4)));

#define B_SZ   4
#define S_LEN  2048
#define D_DIM  1024
#define NH     16
#define DKH    64
#define M_ROWS (B_SZ * S_LEN)   // 8192

// softmax scale folded into exp2 domain: 1/sqrt(64) * log2(e)
#define C_SC 0.1803368801111204f
// defer-max threshold in raw-score units: 8 / C_SC  (P bounded by 2^8)
#define DEFER_THR 44.36f

// kv/q row owned by (reg r, lane-half hf) in a 32x32 MFMA C/D fragment
#define KVLOC(r, hf) ((((r) & 3)) + 8 * ((r) >> 2) + 4 * (hf))

static __device__ __forceinline__ u16 f2bf(float f) {
  return __builtin_bit_cast(u16, (__bf16)f);
}

// pack two f32 -> dword of 2 bf16, element0 in low bits (compiler-generated)
static __device__ __forceinline__ u32 pk2(float lo, float hi) {
  ushort2 u = { f2bf(lo), f2bf(hi) };
  return __builtin_bit_cast(u32, u);
}

static __device__ __forceinline__ float fexp2(float x) {
  return __builtin_amdgcn_exp2f(x);
}

static __device__ __forceinline__ f32x4 mfma16(bf16x8 a, bf16x8 b, f32x4 c) {
  return __builtin_amdgcn_mfma_f32_16x16x32_bf16(a, b, c, 0, 0, 0);
}

static __device__ __forceinline__ f32x16 mfma32(bf16x8 a, bf16x8 b, f32x16 c) {
  return __builtin_amdgcn_mfma_f32_32x32x16_bf16(a, b, c, 0, 0, 0);
}

static __device__ __forceinline__ void gld_lds16(const u16* g, u16* l) {
  __builtin_amdgcn_global_load_lds(
      (const __attribute__((address_space(1))) u32*)g,
      (__attribute__((address_space(3))) u32*)l, 16, 0, 0);
}

// workgroup barrier that drains LDS ops only — outstanding global loads
// (vmcnt) survive across it when desired.
static __device__ __forceinline__ void wg_barrier() {
  asm volatile("s_waitcnt lgkmcnt(0)" ::: "memory");
  __builtin_amdgcn_s_barrier();
  __builtin_amdgcn_sched_barrier(0);
}

// XOR swizzle for row-major [R][64] u16 LDS tiles (read side). Write side is
// linear (global_load_lds) with the inverse permutation applied to the
// GLOBAL source address (same involution).
#define SWZ(row, col) (((row) * 64) + (((col) ^ (((row) & 7) << 3))))

// ---------- fused f32 -> bf16 conversion for x + 4 weights ----------
// grid 12288: blocks [0,8192) convert x (2.097M float4), then 4x1024 blocks
// convert Wq/Wk/Wv/Wo (262144 float4 each). Selection is block-uniform.
__global__ void k_cvt_all(const float* __restrict__ x,
                          const float* __restrict__ wq, const float* __restrict__ wk,
                          const float* __restrict__ wv, const float* __restrict__ wo,
                          u16* __restrict__ xb, u16* __restrict__ wqb,
                          u16* __restrict__ wkb, u16* __restrict__ wvb,
                          u16* __restrict__ wob) {
  int bid = blockIdx.x;
  const float* src; u16* dst; int base;
  if (bid < 8192) {
    src = x; dst = xb; base = bid;
  } else {
    int j = bid - 8192, sel = j >> 10;
    src = (sel == 0) ? wq : (sel == 1) ? wk : (sel == 2) ? wv : wo;
    dst = (sel == 0) ? wqb : (sel == 1) ? wkb : (sel == 2) ? wvb : wob;
    base = j & 1023;
  }
  int i = base * 256 + threadIdx.x;
  float4 v = reinterpret_cast<const float4*>(src)[i];
  ushort4 o = { f2bf(v.x), f2bf(v.y), f2bf(v.z), f2bf(v.w) };
  reinterpret_cast<ushort4*>(dst)[i] = o;
}

// ---------- RoPE table: tab[s*32+k] = (cos, sin) of s * 10000^(-k/32) ----------
__global__ void k_table(float2* __restrict__ tab) {
  int i = blockIdx.x * blockDim.x + threadIdx.x;   // 65536 total
  int s = i >> 5, k = i & 31;
  float freq = powf(10000.0f, -(float)k / 32.0f);
  float a = (float)s * freq;
  tab[i] = make_float2(cosf(a), sinf(a));
}

// ---------- shared 128x128xK GEMM core: C = A(M0 tile) * W^T(N0 tile) ----------
static __device__ __forceinline__ void gemm_tile(
    const u16* __restrict__ A, const u16* __restrict__ W,
    int M0, int N0, u16* As, u16* Bs, f32x4 acc[4][4]) {
  int tid = threadIdx.x;
  int lane = tid & 63, wave = tid >> 6;
  int cl = lane & 15, gp = lane >> 4;
  int wr = wave >> 1, wc = wave & 1;
  for (int t = 0; t < 16; ++t) {
    int k0 = t * 64;
#pragma unroll
    for (int i = 0; i < 4; ++i) {
      int chunk = i * 4 + wave;              // 0..15, wave-uniform
      int rowA  = chunk * 8 + (lane >> 3);   // 0..127
      int col   = (lane & 7) * 8;            // 0..56
      gld_lds16(A + (size_t)(M0 + rowA) * D_DIM + k0 + col, As + chunk * 512);
      gld_lds16(W + (size_t)(N0 + rowA) * D_DIM + k0 + col, Bs + chunk * 512);
    }
    __syncthreads();
#pragma unroll
    for (int kk = 0; kk < 2; ++kk) {
      bf16x8 af[4], bfr[4];
#pragma unroll
      for (int m = 0; m < 4; ++m)
        af[m] = *reinterpret_cast<const bf16x8*>(As + (wr*64 + m*16 + cl)*64 + kk*32 + gp*8);
#pragma unroll
      for (int n = 0; n < 4; ++n)
        bfr[n] = *reinterpret_cast<const bf16x8*>(Bs + (wc*64 + n*16 + cl)*64 + kk*32 + gp*8);
#pragma unroll
      for (int m = 0; m < 4; ++m)
#pragma unroll
        for (int n = 0; n < 4; ++n)
          acc[m][n] = mfma16(af[m], bfr[n], acc[m][n]);
    }
    __syncthreads();
  }
}

// ---------- QKV projection + RoPE + layout ----------
__global__ __launch_bounds__(256)
void k_gemm_qkv(const u16* __restrict__ Xb,
                const u16* __restrict__ Wqb, const u16* __restrict__ Wkb,
                const u16* __restrict__ Wvb,
                const float2* __restrict__ tab,
                u16* __restrict__ Qr, u16* __restrict__ Kr, u16* __restrict__ Vt) {
  __shared__ u16 As[128 * 64];
  __shared__ u16 Bs[128 * 64];
  int by   = blockIdx.y;
  int proj = by >> 3;
  int N0   = (by & 7) * 128;
  int M0   = blockIdx.x * 128;
  const u16* W = (proj == 0) ? Wqb : ((proj == 1) ? Wkb : Wvb);

  f32x4 zero = {0.f, 0.f, 0.f, 0.f};
  f32x4 acc[4][4];
#pragma unroll
  for (int m = 0; m < 4; ++m)
#pragma unroll
    for (int n = 0; n < 4; ++n) acc[m][n] = zero;

  gemm_tile(Xb, W, M0, N0, As, Bs, acc);

  int tid = threadIdx.x, lane = tid & 63, wave = tid >> 6;
  int cl = lane & 15, gp = lane >> 4;
  int wr = wave >> 1, wc = wave & 1;

  if (proj < 2) {
    u16* dst = (proj == 0) ? Qr : Kr;
#pragma unroll
    for (int m = 0; m < 4; ++m) {
#pragma unroll
      for (int n = 0; n < 4; ++n) {
        int colo = N0 + wc*64 + n*16 + cl;        // 0..1023
        int h = colo >> 6, dk = colo & 63;
        int kf = dk >> 1, par = dk & 1;
#pragma unroll
        for (int r = 0; r < 4; ++r) {
          int row = M0 + wr*64 + m*16 + gp*4 + r;  // global (b*S+s)
          int b = row >> 11, sp = row & (S_LEN - 1);
          float v = acc[m][n][r];
          float p = __shfl_xor(v, 1);              // partner column (2k<->2k+1)
          float2 cs = tab[sp * 32 + kf];
          float o = par ? (v * cs.x + p * cs.y) : (v * cs.x - p * cs.y);
          dst[((size_t)(b * NH + h) * S_LEN + sp) * DKH + dk] = f2bf(o);
        }
      }
    }
  } else {
#pragma unroll
    for (int m = 0; m < 4; ++m) {
#pragma unroll
      for (int n = 0; n < 4; ++n) {
        int colo = N0 + wc*64 + n*16 + cl;
        int h = colo >> 6, dk = colo & 63;
        int row0 = M0 + wr*64 + m*16 + gp*4;       // 4 consecutive s
        int b = row0 >> 11, sp0 = row0 & (S_LEN - 1);
        ushort4 o4 = { f2bf(acc[m][n][0]), f2bf(acc[m][n][1]),
                       f2bf(acc[m][n][2]), f2bf(acc[m][n][3]) };
        *reinterpret_cast<ushort4*>(
            Vt + ((size_t)(b * NH + h) * DKH + dk) * S_LEN + sp0) = o4;
      }
    }
  }
}

// ---------- flash attention, causal, 32x32 swapped-QK in-register softmax ----
// grid 512 (1-D, XCD-aware): xcd = id&7 owns bh group (id&7)*8 + (slot>>3);
// qb = 7 - (slot&7) (big blocks first). All 8 q-blocks of a bh live on one
// XCD -> its K/V stays L2-resident (8 bh x 512 KB = 4 MB/XCD).
// 8 waves x 32 q-rows = 256 q/block. KV tile 64, double-buffered LDS via
// global_load_lds DMA with source-side swizzle; PV reads V kv-permuted so
// the P fragment needs NO cross-lane exchange. Softmax exp2+pack fused
// into the PV loop (no p[] array).
__global__ __launch_bounds__(512, 4)
void k_attn(const u16* __restrict__ Q, const u16* __restrict__ K,
            const u16* __restrict__ Vt, u16* __restrict__ Ob) {
  __shared__ u16 Ks[2][64 * 64];
  __shared__ u16 Vs[2][64 * 64];
  __shared__ float lbc[8][32];

  const int tid = threadIdx.x, lane = tid & 63, w = tid >> 6;   // w 0..7
  const int rl = lane & 31, hf = lane >> 5;
  const int id   = blockIdx.x;
  const int slot = id >> 3;                  // 0..63 within XCD
  const int bh   = ((id & 7) << 3) | (slot >> 3);
  const int qb   = 7 - (slot & 7);           // big first within bh group
  const u16* Qb = Q  + (size_t)bh * S_LEN * DKH;
  const u16* Kb = K  + (size_t)bh * S_LEN * DKH;
  const u16* Vb = Vt + (size_t)bh * DKH * S_LEN;
  const int b = bh >> 4, hd = bh & 15;

  // DMA staging: wave w stages rows w*8..w*8+7 of K and of V^T (1 KB each).
  // LDS dest is linear (base + lane*16B); the swizzle permutes the GLOBAL
  // source column-group instead: lane l reads col-group (l&7)^(l>>3) of
  // row (l>>3) — the same involution the SWZ read applies.
  const int lr = lane >> 3;                  // 0..7
  const int lg = (lane & 7) ^ lr;            // swizzled col group
  const u16* kb_l = Kb + (w * 8 + lr) * DKH + lg * 8;
  const u16* vb_l = Vb + (size_t)(w * 8 + lr) * S_LEN + lg * 8;

#define STAGE(buf_, t_) do {                                                 \
    gld_lds16(kb_l + (size_t)(t_) * 64 * DKH, &Ks[buf_][(w * 8) * 64]);      \
    gld_lds16(vb_l + (t_) * 64,               &Vs[buf_][(w * 8) * 64]);      \
  } while (0)

  const int T    = 4 * qb + 4;               // KV tiles
  const int qw32 = qb * 256 + w * 32;        // wave's q base
  const int diag = qw32 >> 6;                // wave's diagonal KV tile

  // Q fragments: lane rl = q-row, hf selects 8-wide k half of each 16-slice
  bf16x8 qf[4];
  {
    const u16* qp = Qb + (size_t)(qw32 + rl) * DKH + hf * 8;
#pragma unroll
    for (int s = 0; s < 4; ++s)
      qf[s] = *reinterpret_cast<const bf16x8*>(qp + s * 16);
  }

  f32x16 o0, o1;
#pragma unroll
  for (int r = 0; r < 16; ++r) { o0[r] = 0.f; o1[r] = 0.f; }
  float m = -1e30f, plr = 0.f;

  // prologue: tile 0 DMA, drain, barrier
  STAGE(0, 0);
  asm volatile("s_waitcnt vmcnt(0)" ::: "memory");
  __builtin_amdgcn_s_barrier();

  int cur = 0;
#pragma unroll 1
  for (int t = 0; t < T; ++t) {
    // issue next tile's DMA into the other buffer (prev reads drained at
    // the barrier that opened this tile)
    if (t + 1 < T) STAGE(cur ^ 1, t + 1);

    const bool act = (t <= diag);

    if (act) {
      f32x16 s0, s1;
#pragma unroll
      for (int r = 0; r < 16; ++r) { s0[r] = 0.f; s1[r] = 0.f; }
      __builtin_amdgcn_s_setprio(1);
#pragma unroll
      for (int s = 0; s < 4; ++s) {
        bf16x8 k0 = *reinterpret_cast<const bf16x8*>(
            &Ks[cur][SWZ(rl,      s * 16 + hf * 8)]);
        bf16x8 k1 = *reinterpret_cast<const bf16x8*>(
            &Ks[cur][SWZ(32 + rl, s * 16 + hf * 8)]);
        s0 = mfma32(k0, qf[s], s0);
        s1 = mfma32(k1, qf[s], s1);
      }
      __builtin_amdgcn_s_setprio(0);

      // causal mask, diagonal tile only
      if (t == diag) {
        const int qrel = qw32 + rl - t * 64;
#pragma unroll
        for (int r = 0; r < 16; ++r) {
          const int kl = KVLOC(r, hf);
          if (kl > qrel)      s0[r] = -1e30f;
          if (32 + kl > qrel) s1[r] = -1e30f;
        }
      }

      // row max: in-lane tree + half-fold (q-row rl lives on lanes rl, rl+32)
      float v[16];
#pragma unroll
      for (int r = 0; r < 16; ++r) v[r] = fmaxf(s0[r], s1[r]);
#pragma unroll
      for (int st = 8; st >= 1; st >>= 1)
#pragma unroll
        for (int r = 0; r < 8; ++r)
          if (r < st) v[r] = fmaxf(v[r], v[r + st]);
      const float mx = fmaxf(v[0], __shfl_xor(v[0], 32));

      if (__any(mx > m + DEFER_THR)) {       // rescale (first tile; then rare)
        const float mn = fmaxf(m, mx);
        const float al = fexp2((m - mn) * C_SC);
        m = mn;
        plr *= al;
        lbc[w][rl] = al;                     // lane-space -> reg-space bridge
        asm volatile("s_waitcnt lgkmcnt(0)" ::: "memory");
#pragma unroll
        for (int r = 0; r < 16; ++r) {
          const float alr = lbc[w][KVLOC(r, hf)];
          o0[r] *= alr; o1[r] *= alr;
        }
      }

      // ---- fused softmax-finish + PV ----
      // For s-step s: exp2 the 8 score regs (from s0 if s<2 else s1, reg
      // base (s&1)*8), accumulate row-sum, pack to bf16, MFMA with V read
      // kv-permuted (slot e <-> kv 4hf+(e&3)+8(e>>2)) so P needs no
      // cross-lane exchange.
      const float mC = m * C_SC;
      float sv = 0.f;
#pragma unroll
      for (int s = 0; s < 4; ++s) {
        const int r0 = (s & 1) * 8;
        float e0, e1, e2, e3, e4, e5, e6, e7;
        if (s < 2) {
          e0 = fexp2(fmaf(s0[r0+0], C_SC, -mC)); e1 = fexp2(fmaf(s0[r0+1], C_SC, -mC));
          e2 = fexp2(fmaf(s0[r0+2], C_SC, -mC)); e3 = fexp2(fmaf(s0[r0+3], C_SC, -mC));
          e4 = fexp2(fmaf(s0[r0+4], C_SC, -mC)); e5 = fexp2(fmaf(s0[r0+5], C_SC, -mC));
          e6 = fexp2(fmaf(s0[r0+6], C_SC, -mC)); e7 = fexp2(fmaf(s0[r0+7], C_SC, -mC));
        } else {
          e0 = fexp2(fmaf(s1[r0+0], C_SC, -mC)); e1 = fexp2(fmaf(s1[r0+1], C_SC, -mC));
          e2 = fexp2(fmaf(s1[r0+2], C_SC, -mC)); e3 = fexp2(fmaf(s1[r0+3], C_SC, -mC));
          e4 = fexp2(fmaf(s1[r0+4], C_SC, -mC)); e5 = fexp2(fmaf(s1[r0+5], C_SC, -mC));
          e6 = fexp2(fmaf(s1[r0+6], C_SC, -mC)); e7 = fexp2(fmaf(s1[r0+7], C_SC, -mC));
        }
        sv += ((e0 + e1) + (e2 + e3)) + ((e4 + e5) + (e6 + e7));
        u32x4 fw = { pk2(e0, e1), pk2(e2, e3), pk2(e4, e5), pk2(e6, e7) };
        bf16x8 af = __builtin_bit_cast(bf16x8, fw);
        uint2 va = *reinterpret_cast<const uint2*>(
            &Vs[cur][SWZ(rl,      s * 16 + 4 * hf)]);
        uint2 vb = *reinterpret_cast<const uint2*>(
            &Vs[cur][SWZ(rl,      s * 16 + 8 + 4 * hf)]);
        uint2 vc = *reinterpret_cast<const uint2*>(
            &Vs[cur][SWZ(32 + rl, s * 16 + 4 * hf)]);
        uint2 vd = *reinterpret_cast<const uint2*>(
            &Vs[cur][SWZ(32 + rl, s * 16 + 8 + 4 * hf)]);
        u32x4 v0w = { va.x, va.y, vb.x, vb.y };
        u32x4 v1w = { vc.x, vc.y, vd.x, vd.y };
        bf16x8 v0 = __builtin_bit_cast(bf16x8, v0w);
        bf16x8 v1 = __builtin_bit_cast(bf16x8, v1w);
        __builtin_amdgcn_s_setprio(1);
        o0 = mfma32(af, v0, o0);
        o1 = mfma32(af, v1, o1);
        __builtin_amdgcn_s_setprio(0);
      }
      plr += sv;
    }

    // next tile's DMA must be complete before anyone reads it
    asm volatile("s_waitcnt vmcnt(0)" ::: "memory");
    wg_barrier();
    cur ^= 1;
  }

  // epilogue: fold row sums, bridge 1/l to reg-space, store
  const float lsum = plr + __shfl_xor(plr, 32);
  lbc[w][rl] = 1.0f / lsum;
  asm volatile("s_waitcnt lgkmcnt(0)" ::: "memory");
#pragma unroll
  for (int r = 0; r < 16; ++r) {
    const float ivr = lbc[w][KVLOC(r, hf)];
    const int q = qw32 + KVLOC(r, hf);
    u16* op = Ob + ((size_t)(b * S_LEN + q)) * D_DIM + hd * DKH;
    op[rl]      = f2bf(o0[r] * ivr);
    op[32 + rl] = f2bf(o1[r] * ivr);
  }
#undef STAGE
}

// ---------- output projection: out = attn * Wo^T, f32 stores ----------
__global__ __launch_bounds__(256)
void k_gemm_out(const u16* __restrict__ Ab, const u16* __restrict__ Wob,
                float* __restrict__ out) {
  __shared__ u16 As[128 * 64];
  __shared__ u16 Bs[128 * 64];
  int M0 = blockIdx.x * 128, N0 = blockIdx.y * 128;
  f32x4 zero = {0.f, 0.f, 0.f, 0.f};
  f32x4 acc[4][4];
#pragma unroll
  for (int m = 0; m < 4; ++m)
#pragma unroll
    for (int n = 0; n < 4; ++n) acc[m][n] = zero;

  gemm_tile(Ab, Wob, M0, N0, As, Bs, acc);

  int tid = threadIdx.x, lane = tid & 63, wave = tid >> 6;
  int cl = lane & 15, gp = lane >> 4;
  int wr = wave >> 1, wc = wave & 1;
#pragma unroll
  for (int m = 0; m < 4; ++m)
#pragma unroll
    for (int n = 0; n < 4; ++n)
#pragma unroll
      for (int r = 0; r < 4; ++r) {
        int row = M0 + wr*64 + m*16 + gp*4 + r;
        int col = N0 + wc*64 + n*16 + cl;
        out[(size_t)row * D_DIM + col] = acc[m][n][r];
      }
}

extern "C" void kernel_launch(void* const* d_in, const int* in_sizes, int n_in,
                              void* d_out, int out_size, void* d_ws, size_t ws_size,
                              hipStream_t stream) {
  const float* x  = (const float*)d_in[0];
  const float* Wq = (const float*)d_in[1];
  const float* Wk = (const float*)d_in[2];
  const float* Wv = (const float*)d_in[3];
  const float* Wo = (const float*)d_in[4];
  float* out = (float*)d_out;

  char* ws = (char*)d_ws;
  size_t off = 0;
  u16* xb  = (u16*)(ws + off); off += (size_t)M_ROWS * D_DIM * 2;   // 16 MB
  u16* wqb = (u16*)(ws + off); off += (size_t)D_DIM * D_DIM * 2;    // 2 MB
  u16* wkb = (u16*)(ws + off); off += (size_t)D_DIM * D_DIM * 2;
  u16* wvb = (u16*)(ws + off); off += (size_t)D_DIM * D_DIM * 2;
  u16* wob = (u16*)(ws + off); off += (size_t)D_DIM * D_DIM * 2;
  float2* tab = (float2*)(ws + off); off += (size_t)S_LEN * 32 * 8; // 0.5 MB
  u16* Qr = (u16*)(ws + off); off += (size_t)M_ROWS * D_DIM * 2;    // 16 MB
  u16* Kr = (u16*)(ws + off); off += (size_t)M_ROWS * D_DIM * 2;
  u16* Vt = (u16*)(ws + off); off += (size_t)M_ROWS * D_DIM * 2;
  u16* Ab = (u16*)(ws + off); off += (size_t)M_ROWS * D_DIM * 2;
  (void)ws_size; (void)in_sizes; (void)n_in; (void)out_size;

  k_cvt_all<<<12288, 256, 0, stream>>>(x, Wq, Wk, Wv, Wo, xb, wqb, wkb, wvb, wob);
  k_table<<<256, 256, 0, stream>>>(tab);

  k_gemm_qkv<<<dim3(64, 24), 256, 0, stream>>>(xb, wqb, wkb, wvb, tab, Qr, Kr, Vt);
  k_attn<<<dim3(512), 512, 0, stream>>>(Qr, Kr, Vt, Ab);
  k_gemm_out<<<dim3(64, 8), 256, 0, stream>>>(Ab, wob, out);
}